// Round 1
// baseline (1193.934 us; speedup 1.0000x reference)
//
#include <hip/hip_runtime.h>
#include <hip/hip_bf16.h>

// ---------------------------------------------------------------------------
// GAT (3 layers) + global mean pool + linear head.
// Strategy: build CSR over dst (incl. self-loops) once per call, then per
// layer: f32 tiled GEMM -> per-node (al_src, al_dst) -> per-node block
// softmax-aggregate (no global atomics). Finally pool + tiny GEMM.
// ---------------------------------------------------------------------------

#define LRELU(x) ((x) >= 0.f ? (x) : 0.2f * (x))

// ---------------- CSR build ----------------

__global__ void deg_kernel(const int* __restrict__ dst, int* __restrict__ deg,
                           int E, int N) {
    int i = blockIdx.x * blockDim.x + threadIdx.x;
    if (i < E) atomicAdd(&deg[dst[i]], 1);
    else if (i < E + N) atomicAdd(&deg[i - E], 1);   // self loop
}

__global__ void scan_kernel(const int* __restrict__ deg, int* __restrict__ rowptr,
                            int n) {
    __shared__ int partial[1024];
    const int tid = threadIdx.x;
    const int chunk = (n + 1023) / 1024;
    const int start = min(tid * chunk, n);
    const int end = min(start + chunk, n);
    int s = 0;
    for (int i = start; i < end; i++) s += deg[i];
    partial[tid] = s;
    __syncthreads();
    for (int o = 1; o < 1024; o <<= 1) {
        int v = (tid >= o) ? partial[tid - o] : 0;
        __syncthreads();
        partial[tid] += v;
        __syncthreads();
    }
    int run = (tid == 0) ? 0 : partial[tid - 1];
    for (int i = start; i < end; i++) { rowptr[i] = run; run += deg[i]; }
    if (tid == 0) rowptr[n] = partial[1023];
}

__global__ void scatter_kernel(const int* __restrict__ src, const int* __restrict__ dst,
                               const int* __restrict__ rowptr, int* __restrict__ fill,
                               int* __restrict__ col, int E, int N) {
    int i = blockIdx.x * blockDim.x + threadIdx.x;
    int s, d;
    if (i < E) { s = src[i]; d = dst[i]; }
    else if (i < E + N) { s = i - E; d = s; }
    else return;
    int pos = rowptr[d] + atomicAdd(&fill[d], 1);
    col[pos] = s;
}

// ---------------- f32 tiled GEMM: C[M,N] = A[M,K] @ B[K,N] ----------------

template <int BM, int BN, int BK, int TM, int TN>
__global__ __launch_bounds__((BM / TM) * (BN / TN))
void gemm_f32_kernel(const float* __restrict__ A, const float* __restrict__ B,
                     float* __restrict__ C, int M, int N, int K) {
    constexpr int TX = BN / TN;
    constexpr int NT = (BM / TM) * (BN / TN);
    __shared__ float As[BK][BM + 1];
    __shared__ float Bs[BK][BN];
    const int bx = blockIdx.x * BN;
    const int by = blockIdx.y * BM;
    const int tid = threadIdx.x;
    const int tx = tid % TX;
    const int ty = tid / TX;
    float acc[TM][TN] = {};
    for (int k0 = 0; k0 < K; k0 += BK) {
        for (int i = tid; i < BM * BK; i += NT) {
            int m = i / BK, kk = i % BK;
            int gm = by + m;
            As[kk][m] = (gm < M) ? A[(size_t)gm * K + (k0 + kk)] : 0.f;
        }
        for (int i = tid; i < BK * BN; i += NT) {
            int kk = i / BN, nn = i % BN;
            Bs[kk][nn] = B[(size_t)(k0 + kk) * N + (bx + nn)];  // K,N multiples of BK,BN
        }
        __syncthreads();
#pragma unroll
        for (int kk = 0; kk < BK; kk++) {
            float a[TM], b[TN];
#pragma unroll
            for (int i = 0; i < TM; i++) a[i] = As[kk][ty * TM + i];
#pragma unroll
            for (int j = 0; j < TN; j++) b[j] = Bs[kk][tx * TN + j];
#pragma unroll
            for (int i = 0; i < TM; i++)
#pragma unroll
                for (int j = 0; j < TN; j++) acc[i][j] += a[i] * b[j];
        }
        __syncthreads();
    }
    for (int i = 0; i < TM; i++) {
        int gm = by + ty * TM + i;
        if (gm < M) {
            for (int j = 0; j < TN; j++)
                C[(size_t)gm * N + bx + tx * TN + j] = acc[i][j];
        }
    }
}

// ---------------- per-node attention logits ----------------

template <int H, int C>
__global__ void al_kernel(const float* __restrict__ hfeat, const float* __restrict__ a_src,
                          const float* __restrict__ a_dst, float* __restrict__ als,
                          float* __restrict__ ald, int N) {
    int i = blockIdx.x * blockDim.x + threadIdx.x;
    if (i >= N * H) return;
    int n = i / H, h = i % H;
    const float* hp = hfeat + (size_t)n * H * C + h * C;
    float s1 = 0.f, s2 = 0.f;
    for (int c = 0; c < C; c++) {
        float v = hp[c];
        s1 += v * a_src[h * C + c];
        s2 += v * a_dst[h * C + c];
    }
    als[i] = s1;
    ald[i] = s2;
}

// ---------------- per-node softmax + aggregate ----------------

template <int H, int C, bool RELU>
__global__ __launch_bounds__((H * C < 64) ? 64 : H * C)
void gat_agg_kernel(const float* __restrict__ hfeat, const float* __restrict__ als,
                    const float* __restrict__ ald, const int* __restrict__ rowptr,
                    const int* __restrict__ col, const float* __restrict__ bias,
                    float* __restrict__ out, int N) {
    constexpr int HC = H * C;
    constexpr int BLOCK = (HC < 64) ? 64 : HC;
    constexpr int CHUNK = BLOCK / H;
    constexpr int LOG2H = (H == 8) ? 3 : 0;

    const int n = blockIdx.x;
    const int tid = threadIdx.x;
    const int r0 = rowptr[n];
    const int deg = rowptr[n + 1] - r0;

    __shared__ float sald[H];
    __shared__ float smax[H];
    __shared__ float sinv[H];
    __shared__ float red[BLOCK];
    __shared__ float wts[CHUNK * H];
    __shared__ int scol[CHUNK];

    if (tid < H) sald[tid] = ald[(size_t)n * H + tid];
    __syncthreads();

    const int hw = tid & (H - 1);

    // pass 1a: per-head max
    float lmax = -INFINITY;
    for (int idx = tid; idx < deg * H; idx += BLOCK) {
        int j = idx >> LOG2H;
        int s = col[r0 + j];
        float e = als[(size_t)s * H + hw] + sald[hw];
        e = LRELU(e);
        lmax = fmaxf(lmax, e);
    }
    red[tid] = lmax;
    __syncthreads();
    for (int s = BLOCK / 2; s >= H; s >>= 1) {
        if (tid < s) red[tid] = fmaxf(red[tid], red[tid + s]);
        __syncthreads();
    }
    if (tid < H) smax[tid] = red[tid];
    __syncthreads();

    // pass 1b: per-head sum of exp
    const float mh = smax[hw];
    float lsum = 0.f;
    for (int idx = tid; idx < deg * H; idx += BLOCK) {
        int j = idx >> LOG2H;
        int s = col[r0 + j];
        float e = als[(size_t)s * H + hw] + sald[hw];
        e = LRELU(e);
        lsum += expf(e - mh);
    }
    __syncthreads();
    red[tid] = lsum;
    __syncthreads();
    for (int s = BLOCK / 2; s >= H; s >>= 1) {
        if (tid < s) red[tid] += red[tid + s];
        __syncthreads();
    }
    if (tid < H) sinv[tid] = 1.0f / red[tid];
    __syncthreads();

    // pass 2: weighted accumulation
    float acc = 0.f;
    const int ha = tid / C;
    for (int base = 0; base < deg; base += CHUNK) {
        int m = min(CHUNK, deg - base);
        __syncthreads();  // protect scol/wts from readers of previous iteration
        if (tid < CHUNK && tid < m) scol[tid] = col[r0 + base + tid];
        __syncthreads();
        int jw = tid >> LOG2H;
        if (jw < m) {
            int s = scol[jw];
            float e = als[(size_t)s * H + hw] + sald[hw];
            e = LRELU(e);
            wts[jw * H + hw] = expf(e - smax[hw]) * sinv[hw];
        }
        __syncthreads();
        if (tid < HC) {
            for (int j = 0; j < m; j++)
                acc += hfeat[(size_t)scol[j] * HC + tid] * wts[j * H + ha];
        }
    }
    if (tid < HC) {
        float v = acc + bias[tid];
        if (RELU) v = fmaxf(v, 0.f);
        out[(size_t)n * HC + tid] = v;
    }
}

// ---------------- pooling + head ----------------

__global__ void pool_kernel(const float* __restrict__ h, const int* __restrict__ batch,
                            float* __restrict__ sums, int* __restrict__ cnt, int N) {
    int i = blockIdx.x * blockDim.x + threadIdx.x;
    if (i >= N * 32) return;
    int n = i >> 5, c = i & 31;
    int g = batch[n];
    atomicAdd(&sums[g * 32 + c], h[i]);
    if (c == 0) atomicAdd(&cnt[g], 1);
}

__global__ void final_kernel(const float* __restrict__ sums, const int* __restrict__ cnt,
                             const float* __restrict__ lin_w, const float* __restrict__ lin_b,
                             float* __restrict__ out) {
    int g = blockIdx.x;
    int o = threadIdx.x;  // 64
    __shared__ float p[32];
    if (o < 32) {
        float cn = fmaxf((float)cnt[g], 1.0f);
        p[o] = sums[g * 32 + o] / cn;
    }
    __syncthreads();
    float acc = lin_b[o];
    for (int c = 0; c < 32; c++) acc += p[c] * lin_w[c * 64 + o];
    out[g * 64 + o] = acc;
}

// ---------------- launch ----------------

extern "C" void kernel_launch(void* const* d_in, const int* in_sizes, int n_in,
                              void* d_out, int out_size, void* d_ws, size_t ws_size,
                              hipStream_t stream) {
    const float* x     = (const float*)d_in[0];
    const int*   ei    = (const int*)d_in[1];
    const int*   batch = (const int*)d_in[2];
    const float* W0    = (const float*)d_in[3];
    const float* a_s0  = (const float*)d_in[4];
    const float* a_d0  = (const float*)d_in[5];
    const float* b0    = (const float*)d_in[6];
    const float* W1    = (const float*)d_in[7];
    const float* a_s1  = (const float*)d_in[8];
    const float* a_d1  = (const float*)d_in[9];
    const float* b1    = (const float*)d_in[10];
    const float* W2    = (const float*)d_in[11];
    const float* a_s2  = (const float*)d_in[12];
    const float* a_d2  = (const float*)d_in[13];
    const float* b2    = (const float*)d_in[14];
    const float* lin_w = (const float*)d_in[15];
    const float* lin_b = (const float*)d_in[16];

    const int N = in_sizes[0] / 128;   // 50000
    const int E = in_sizes[1] / 2;     // 1600000
    const int Etot = E + N;            // with self loops
    const int* src = ei;
    const int* dst = ei + E;

    char* w = (char*)d_ws;
    size_t off = 0;
    auto alloc = [&](size_t bytes) -> void* {
        void* p = (void*)(w + off);
        off += (bytes + 255) & ~(size_t)255;
        return p;
    };
    int*   deg    = (int*)alloc((size_t)N * 4);
    int*   rowptr = (int*)alloc((size_t)(N + 1) * 4);
    int*   fill   = (int*)alloc((size_t)N * 4);
    int*   colA   = (int*)alloc((size_t)Etot * 4);
    float* als    = (float*)alloc((size_t)N * 8 * 4);
    float* ald    = (float*)alloc((size_t)N * 8 * 4);
    float* bufA   = (float*)alloc((size_t)N * 256 * 4);
    float* bufB   = (float*)alloc((size_t)N * 256 * 4);
    float* h2     = (float*)alloc((size_t)N * 32 * 4);
    float* out2   = (float*)alloc((size_t)N * 32 * 4);
    float* sums   = (float*)alloc((size_t)256 * 32 * 4);
    int*   cnt    = (int*)alloc((size_t)256 * 4);

    hipMemsetAsync(deg, 0, (size_t)N * 4, stream);
    hipMemsetAsync(fill, 0, (size_t)N * 4, stream);
    hipMemsetAsync(sums, 0, (size_t)256 * 32 * 4, stream);
    hipMemsetAsync(cnt, 0, (size_t)256 * 4, stream);

    // CSR by dst (with self loops)
    deg_kernel<<<(Etot + 255) / 256, 256, 0, stream>>>(dst, deg, E, N);
    scan_kernel<<<1, 1024, 0, stream>>>(deg, rowptr, N);
    scatter_kernel<<<(Etot + 255) / 256, 256, 0, stream>>>(src, dst, rowptr, fill, colA, E, N);

    dim3 g256(256 / 64, (N + 63) / 64);
    dim3 g32(1, (N + 63) / 64);

    // layer 0
    gemm_f32_kernel<64, 64, 16, 4, 4><<<g256, 256, 0, stream>>>(x, W0, bufA, N, 256, 128);
    al_kernel<8, 32><<<(N * 8 + 255) / 256, 256, 0, stream>>>(bufA, a_s0, a_d0, als, ald, N);
    gat_agg_kernel<8, 32, true><<<N, 256, 0, stream>>>(bufA, als, ald, rowptr, colA, b0, bufB, N);

    // layer 1
    gemm_f32_kernel<64, 64, 16, 4, 4><<<g256, 256, 0, stream>>>(bufB, W1, bufA, N, 256, 256);
    al_kernel<8, 32><<<(N * 8 + 255) / 256, 256, 0, stream>>>(bufA, a_s1, a_d1, als, ald, N);
    gat_agg_kernel<8, 32, true><<<N, 256, 0, stream>>>(bufA, als, ald, rowptr, colA, b1, bufB, N);

    // layer 2 (heads=1, C=32)
    gemm_f32_kernel<64, 32, 16, 4, 2><<<g32, 256, 0, stream>>>(bufB, W2, h2, N, 32, 256);
    al_kernel<1, 32><<<(N + 255) / 256, 256, 0, stream>>>(h2, a_s2, a_d2, als, ald, N);
    gat_agg_kernel<1, 32, false><<<N, 64, 0, stream>>>(h2, als, ald, rowptr, colA, b2, out2, N);

    // pool + head
    pool_kernel<<<(N * 32 + 255) / 256, 256, 0, stream>>>(out2, batch, sums, cnt, N);
    final_kernel<<<256, 64, 0, stream>>>(sums, cnt, lin_w, lin_b, (float*)d_out);
}

// Round 2
// 1002.555 us; speedup vs baseline: 1.1909x; 1.1909x over previous
//
#include <hip/hip_runtime.h>
#include <hip/hip_bf16.h>

// ---------------------------------------------------------------------------
// GAT (3 layers) + global mean pool + linear head.
// R2: h stored bf16 (halves gather traffic), fused online softmax pass,
// 128x128 f32 GEMM with 8x8 micro-tile.
// ---------------------------------------------------------------------------

#define LRELU(x) ((x) >= 0.f ? (x) : 0.2f * (x))

// ---------------- CSR build ----------------

__global__ void deg_kernel(const int* __restrict__ dst, int* __restrict__ deg,
                           int E, int N) {
    int i = blockIdx.x * blockDim.x + threadIdx.x;
    if (i < E) atomicAdd(&deg[dst[i]], 1);
    else if (i < E + N) atomicAdd(&deg[i - E], 1);   // self loop
}

__global__ void scan_kernel(const int* __restrict__ deg, int* __restrict__ rowptr,
                            int n) {
    __shared__ int partial[1024];
    const int tid = threadIdx.x;
    const int chunk = (n + 1023) / 1024;
    const int start = min(tid * chunk, n);
    const int end = min(start + chunk, n);
    int s = 0;
    for (int i = start; i < end; i++) s += deg[i];
    partial[tid] = s;
    __syncthreads();
    for (int o = 1; o < 1024; o <<= 1) {
        int v = (tid >= o) ? partial[tid - o] : 0;
        __syncthreads();
        partial[tid] += v;
        __syncthreads();
    }
    int run = (tid == 0) ? 0 : partial[tid - 1];
    for (int i = start; i < end; i++) { rowptr[i] = run; run += deg[i]; }
    if (tid == 0) rowptr[n] = partial[1023];
}

__global__ void scatter_kernel(const int* __restrict__ src, const int* __restrict__ dst,
                               const int* __restrict__ rowptr, int* __restrict__ fill,
                               int* __restrict__ col, int E, int N) {
    int i = blockIdx.x * blockDim.x + threadIdx.x;
    int s, d;
    if (i < E) { s = src[i]; d = dst[i]; }
    else if (i < E + N) { s = i - E; d = s; }
    else return;
    int pos = rowptr[d] + atomicAdd(&fill[d], 1);
    col[pos] = s;
}

// ---------------- fast f32 GEMM (bf16 out): 128x128x16, 8x8/thread ----------------

template <int BM, int BN, int BK>
__global__ __launch_bounds__(256)
void gemm128_bf16(const float* __restrict__ A, const float* __restrict__ B,
                  __hip_bfloat16* __restrict__ C, int M, int N, int K) {
    __shared__ float As[BK][BM + 4];
    __shared__ float Bs[BK][BN + 4];
    const int bx = blockIdx.x * BN;
    const int by = blockIdx.y * BM;
    const int tid = threadIdx.x;
    const int tx = tid & 15;        // 16 cols of threads
    const int ty = tid >> 4;        // 16 rows of threads
    float acc[8][8] = {};
    for (int k0 = 0; k0 < K; k0 += BK) {
        // A tile: BM x BK floats, float4 loads, transposed store to LDS
        for (int v = tid; v < BM * BK / 4; v += 256) {
            int row = v / (BK / 4);
            int k4 = (v % (BK / 4)) * 4;
            int gm = by + row;
            float4 val = {0.f, 0.f, 0.f, 0.f};
            if (gm < M) val = *(const float4*)&A[(size_t)gm * K + k0 + k4];
            As[k4 + 0][row] = val.x;
            As[k4 + 1][row] = val.y;
            As[k4 + 2][row] = val.z;
            As[k4 + 3][row] = val.w;
        }
        // B tile: BK x BN floats, float4 loads, contiguous store
        for (int v = tid; v < BK * BN / 4; v += 256) {
            int kk = v / (BN / 4);
            int c4 = (v % (BN / 4)) * 4;
            *(float4*)&Bs[kk][c4] = *(const float4*)&B[(size_t)(k0 + kk) * N + bx + c4];
        }
        __syncthreads();
#pragma unroll
        for (int kk = 0; kk < BK; kk++) {
            float4 a0 = *(float4*)&As[kk][ty * 4];
            float4 a1 = *(float4*)&As[kk][BM / 2 + ty * 4];
            float4 b0 = *(float4*)&Bs[kk][tx * 4];
            float4 b1 = *(float4*)&Bs[kk][BN / 2 + tx * 4];
            float a[8] = {a0.x, a0.y, a0.z, a0.w, a1.x, a1.y, a1.z, a1.w};
            float b[8] = {b0.x, b0.y, b0.z, b0.w, b1.x, b1.y, b1.z, b1.w};
#pragma unroll
            for (int i = 0; i < 8; i++)
#pragma unroll
                for (int j = 0; j < 8; j++) acc[i][j] += a[i] * b[j];
        }
        __syncthreads();
    }
#pragma unroll
    for (int i = 0; i < 8; i++) {
        int gm = by + (i < 4 ? ty * 4 + i : BM / 2 + ty * 4 + (i - 4));
        if (gm >= M) continue;
#pragma unroll
        for (int j = 0; j < 8; j++) {
            int gn = bx + (j < 4 ? tx * 4 + j : BN / 2 + tx * 4 + (j - 4));
            C[(size_t)gm * N + gn] = __float2bfloat16(acc[i][j]);
        }
    }
}

// ---------------- small generic GEMM (bf16 out) for layer 2 ----------------

template <int BM, int BN, int BK, int TM, int TN>
__global__ __launch_bounds__((BM / TM) * (BN / TN))
void gemm_small_bf16(const float* __restrict__ A, const float* __restrict__ B,
                     __hip_bfloat16* __restrict__ C, int M, int N, int K) {
    constexpr int TX = BN / TN;
    constexpr int NT = (BM / TM) * (BN / TN);
    __shared__ float As[BK][BM + 1];
    __shared__ float Bs[BK][BN];
    const int bx = blockIdx.x * BN;
    const int by = blockIdx.y * BM;
    const int tid = threadIdx.x;
    const int tx = tid % TX;
    const int ty = tid / TX;
    float acc[TM][TN] = {};
    for (int k0 = 0; k0 < K; k0 += BK) {
        for (int i = tid; i < BM * BK; i += NT) {
            int m = i / BK, kk = i % BK;
            int gm = by + m;
            As[kk][m] = (gm < M) ? A[(size_t)gm * K + (k0 + kk)] : 0.f;
        }
        for (int i = tid; i < BK * BN; i += NT) {
            int kk = i / BN, nn = i % BN;
            Bs[kk][nn] = B[(size_t)(k0 + kk) * N + (bx + nn)];
        }
        __syncthreads();
#pragma unroll
        for (int kk = 0; kk < BK; kk++) {
            float a[TM], b[TN];
#pragma unroll
            for (int i = 0; i < TM; i++) a[i] = As[kk][ty * TM + i];
#pragma unroll
            for (int j = 0; j < TN; j++) b[j] = Bs[kk][tx * TN + j];
#pragma unroll
            for (int i = 0; i < TM; i++)
#pragma unroll
                for (int j = 0; j < TN; j++) acc[i][j] += a[i] * b[j];
        }
        __syncthreads();
    }
    for (int i = 0; i < TM; i++) {
        int gm = by + ty * TM + i;
        if (gm < M) {
            for (int j = 0; j < TN; j++)
                C[(size_t)gm * N + bx + tx * TN + j] = __float2bfloat16(acc[i][j]);
        }
    }
}

// ---------------- per-node attention logits (bf16 h) ----------------

template <int H, int C>
__global__ void al_bf16(const __hip_bfloat16* __restrict__ hfeat, const float* __restrict__ a_src,
                        const float* __restrict__ a_dst, float* __restrict__ als,
                        float* __restrict__ ald, int N) {
    int i = blockIdx.x * blockDim.x + threadIdx.x;
    if (i >= N * H) return;
    int n = i / H, h = i % H;
    const __hip_bfloat16* hp = hfeat + (size_t)n * H * C + h * C;
    float s1 = 0.f, s2 = 0.f;
    for (int c = 0; c < C; c++) {
        float v = __bfloat162float(hp[c]);
        s1 += v * a_src[h * C + c];
        s2 += v * a_dst[h * C + c];
    }
    als[i] = s1;
    ald[i] = s2;
}

// ---------------- per-node softmax + aggregate (bf16 gather, fused pass1) ----------------

template <int H, int C, bool RELU>
__global__ __launch_bounds__((H * C < 64) ? 64 : H * C)
void gat_agg_bf16(const __hip_bfloat16* __restrict__ hfeat, const float* __restrict__ als,
                  const float* __restrict__ ald, const int* __restrict__ rowptr,
                  const int* __restrict__ col, const float* __restrict__ bias,
                  float* __restrict__ out, int N) {
    constexpr int HC = H * C;
    constexpr int BLOCK = (HC < 64) ? 64 : HC;
    constexpr int CHUNK = BLOCK / H;
    constexpr int LOG2H = (H == 8) ? 3 : 0;

    const int n = blockIdx.x;
    const int tid = threadIdx.x;
    const int r0 = rowptr[n];
    const int deg = rowptr[n + 1] - r0;

    __shared__ float sald[H];
    __shared__ float smax[H];
    __shared__ float sinv[H];
    __shared__ float mred[BLOCK];
    __shared__ float sred[BLOCK];
    __shared__ float wts[CHUNK * H];
    __shared__ int scol[CHUNK];

    if (tid < H) sald[tid] = ald[(size_t)n * H + tid];
    __syncthreads();

    const int hw = tid & (H - 1);
    const float aldh = sald[hw];

    // fused pass 1: online per-head (max, sum-exp)
    float lm = -INFINITY, ls = 0.f;
    for (int idx = tid; idx < deg * H; idx += BLOCK) {
        int j = idx >> LOG2H;
        int s = col[r0 + j];
        float e = als[(size_t)s * H + hw] + aldh;
        e = LRELU(e);
        if (e > lm) {
            ls = ls * __expf(lm - e) + 1.f;   // __expf(-inf)=0 on first hit
            lm = e;
        } else {
            ls += __expf(e - lm);
        }
    }
    mred[tid] = lm;
    sred[tid] = ls;
    __syncthreads();
    for (int s = BLOCK / 2; s >= H; s >>= 1) {
        if (tid < s) {
            float m1 = mred[tid], s1 = sred[tid];
            float m2 = mred[tid + s], s2 = sred[tid + s];
            float m = fmaxf(m1, m2);
            float acc = 0.f;
            if (s1 > 0.f) acc += s1 * __expf(m1 - m);
            if (s2 > 0.f) acc += s2 * __expf(m2 - m);
            mred[tid] = m;
            sred[tid] = acc;
        }
        __syncthreads();
    }
    if (tid < H) {
        smax[tid] = mred[tid];
        sinv[tid] = 1.0f / sred[tid];
    }
    __syncthreads();
    const float mh = smax[hw];
    const float sih = sinv[hw];

    // pass 2: weighted accumulation over bf16 rows
    float acc = 0.f;
    const int ha = tid / C;
    for (int base = 0; base < deg; base += CHUNK) {
        int m = min(CHUNK, deg - base);
        __syncthreads();  // protect scol/wts from previous iteration readers
        if (tid < CHUNK && tid < m) scol[tid] = col[r0 + base + tid];
        __syncthreads();
        int jw = tid >> LOG2H;
        if (jw < m) {
            int s = scol[jw];
            float e = als[(size_t)s * H + hw] + aldh;
            e = LRELU(e);
            wts[jw * H + hw] = __expf(e - mh) * sih;
        }
        __syncthreads();
        if (tid < HC) {
            for (int j = 0; j < m; j++)
                acc += __bfloat162float(hfeat[(size_t)scol[j] * HC + tid]) * wts[j * H + ha];
        }
    }
    if (tid < HC) {
        float v = acc + bias[tid];
        if (RELU) v = fmaxf(v, 0.f);
        out[(size_t)n * HC + tid] = v;
    }
}

// ---------------- pooling + head ----------------

__global__ void pool_kernel(const float* __restrict__ h, const int* __restrict__ batch,
                            float* __restrict__ sums, int* __restrict__ cnt, int N) {
    int i = blockIdx.x * blockDim.x + threadIdx.x;
    if (i >= N * 32) return;
    int n = i >> 5, c = i & 31;
    int g = batch[n];
    atomicAdd(&sums[g * 32 + c], h[i]);
    if (c == 0) atomicAdd(&cnt[g], 1);
}

__global__ void final_kernel(const float* __restrict__ sums, const int* __restrict__ cnt,
                             const float* __restrict__ lin_w, const float* __restrict__ lin_b,
                             float* __restrict__ out) {
    int g = blockIdx.x;
    int o = threadIdx.x;  // 64
    __shared__ float p[32];
    if (o < 32) {
        float cn = fmaxf((float)cnt[g], 1.0f);
        p[o] = sums[g * 32 + o] / cn;
    }
    __syncthreads();
    float acc = lin_b[o];
    for (int c = 0; c < 32; c++) acc += p[c] * lin_w[c * 64 + o];
    out[g * 64 + o] = acc;
}

// ---------------- launch ----------------

extern "C" void kernel_launch(void* const* d_in, const int* in_sizes, int n_in,
                              void* d_out, int out_size, void* d_ws, size_t ws_size,
                              hipStream_t stream) {
    const float* x     = (const float*)d_in[0];
    const int*   ei    = (const int*)d_in[1];
    const int*   batch = (const int*)d_in[2];
    const float* W0    = (const float*)d_in[3];
    const float* a_s0  = (const float*)d_in[4];
    const float* a_d0  = (const float*)d_in[5];
    const float* b0    = (const float*)d_in[6];
    const float* W1    = (const float*)d_in[7];
    const float* a_s1  = (const float*)d_in[8];
    const float* a_d1  = (const float*)d_in[9];
    const float* b1    = (const float*)d_in[10];
    const float* W2    = (const float*)d_in[11];
    const float* a_s2  = (const float*)d_in[12];
    const float* a_d2  = (const float*)d_in[13];
    const float* b2    = (const float*)d_in[14];
    const float* lin_w = (const float*)d_in[15];
    const float* lin_b = (const float*)d_in[16];

    const int N = in_sizes[0] / 128;   // 50000
    const int E = in_sizes[1] / 2;     // 1600000
    const int Etot = E + N;
    const int* src = ei;
    const int* dst = ei + E;

    char* w = (char*)d_ws;
    size_t off = 0;
    auto alloc = [&](size_t bytes) -> void* {
        void* p = (void*)(w + off);
        off += (bytes + 255) & ~(size_t)255;
        return p;
    };
    int*   deg    = (int*)alloc((size_t)N * 4);
    int*   rowptr = (int*)alloc((size_t)(N + 1) * 4);
    int*   fill   = (int*)alloc((size_t)N * 4);
    int*   colA   = (int*)alloc((size_t)Etot * 4);
    float* als    = (float*)alloc((size_t)N * 8 * 4);
    float* ald    = (float*)alloc((size_t)N * 8 * 4);
    __hip_bfloat16* hb = (__hip_bfloat16*)alloc((size_t)N * 256 * 2);  // bf16 h (reused for layer2)
    float* bufB   = (float*)alloc((size_t)N * 256 * 4);                // f32 agg output / GEMM input
    float* out2   = (float*)alloc((size_t)N * 32 * 4);
    float* sums   = (float*)alloc((size_t)256 * 32 * 4);
    int*   cnt    = (int*)alloc((size_t)256 * 4);

    hipMemsetAsync(deg, 0, (size_t)N * 4, stream);
    hipMemsetAsync(fill, 0, (size_t)N * 4, stream);
    hipMemsetAsync(sums, 0, (size_t)256 * 32 * 4, stream);
    hipMemsetAsync(cnt, 0, (size_t)256 * 4, stream);

    // CSR by dst (with self loops)
    deg_kernel<<<(Etot + 255) / 256, 256, 0, stream>>>(dst, deg, E, N);
    scan_kernel<<<1, 1024, 0, stream>>>(deg, rowptr, N);
    scatter_kernel<<<(Etot + 255) / 256, 256, 0, stream>>>(src, dst, rowptr, fill, colA, E, N);

    dim3 gemm_grid(256 / 128, (N + 127) / 128);

    // layer 0: K=128
    gemm128_bf16<128, 128, 16><<<gemm_grid, 256, 0, stream>>>(x, W0, hb, N, 256, 128);
    al_bf16<8, 32><<<(N * 8 + 255) / 256, 256, 0, stream>>>(hb, a_s0, a_d0, als, ald, N);
    gat_agg_bf16<8, 32, true><<<N, 256, 0, stream>>>(hb, als, ald, rowptr, colA, b0, bufB, N);

    // layer 1: K=256
    gemm128_bf16<128, 128, 16><<<gemm_grid, 256, 0, stream>>>(bufB, W1, hb, N, 256, 256);
    al_bf16<8, 32><<<(N * 8 + 255) / 256, 256, 0, stream>>>(hb, a_s1, a_d1, als, ald, N);
    gat_agg_bf16<8, 32, true><<<N, 256, 0, stream>>>(hb, als, ald, rowptr, colA, b1, bufB, N);

    // layer 2: heads=1, C=32 (hb reused as N x 32 bf16)
    gemm_small_bf16<64, 32, 16, 4, 2><<<dim3(1, (N + 63) / 64), 256, 0, stream>>>(bufB, W2, hb, N, 32, 256);
    al_bf16<1, 32><<<(N + 255) / 256, 256, 0, stream>>>(hb, a_s2, a_d2, als, ald, N);
    gat_agg_bf16<1, 32, false><<<N, 64, 0, stream>>>(hb, als, ald, rowptr, colA, b2, out2, N);

    // pool + head
    pool_kernel<<<(N * 32 + 255) / 256, 256, 0, stream>>>(out2, batch, sums, cnt, N);
    final_kernel<<<256, 64, 0, stream>>>(sums, cnt, lin_w, lin_b, (float*)d_out);
}

// Round 3
// 982.277 us; speedup vs baseline: 1.2155x; 1.0206x over previous
//
#include <hip/hip_runtime.h>
#include <hip/hip_bf16.h>

// ---------------------------------------------------------------------------
// GAT (3 layers) + global mean pool + linear head.
// R3: aggregation rebuilt for ILP — 16B vectorized gathers (32 threads/edge),
// e-values cached in LDS (single als pass), normalization in epilogue.
// ---------------------------------------------------------------------------

#define LRELU(x) ((x) >= 0.f ? (x) : 0.2f * (x))

typedef unsigned short ushort8 __attribute__((ext_vector_type(8)));

__device__ __forceinline__ float bf2f(unsigned short u) {
    return __uint_as_float(((unsigned)u) << 16);
}

// ---------------- CSR build ----------------

__global__ void deg_kernel(const int* __restrict__ dst, int* __restrict__ deg,
                           int E, int N) {
    int i = blockIdx.x * blockDim.x + threadIdx.x;
    if (i < E) atomicAdd(&deg[dst[i]], 1);
    else if (i < E + N) atomicAdd(&deg[i - E], 1);   // self loop
}

__global__ void scan_kernel(const int* __restrict__ deg, int* __restrict__ rowptr,
                            int n) {
    __shared__ int partial[1024];
    const int tid = threadIdx.x;
    const int chunk = (n + 1023) / 1024;
    const int start = min(tid * chunk, n);
    const int end = min(start + chunk, n);
    int s = 0;
    for (int i = start; i < end; i++) s += deg[i];
    partial[tid] = s;
    __syncthreads();
    for (int o = 1; o < 1024; o <<= 1) {
        int v = (tid >= o) ? partial[tid - o] : 0;
        __syncthreads();
        partial[tid] += v;
        __syncthreads();
    }
    int run = (tid == 0) ? 0 : partial[tid - 1];
    for (int i = start; i < end; i++) { rowptr[i] = run; run += deg[i]; }
    if (tid == 0) rowptr[n] = partial[1023];
}

__global__ void scatter_kernel(const int* __restrict__ src, const int* __restrict__ dst,
                               const int* __restrict__ rowptr, int* __restrict__ fill,
                               int* __restrict__ col, int E, int N) {
    int i = blockIdx.x * blockDim.x + threadIdx.x;
    int s, d;
    if (i < E) { s = src[i]; d = dst[i]; }
    else if (i < E + N) { s = i - E; d = s; }
    else return;
    int pos = rowptr[d] + atomicAdd(&fill[d], 1);
    col[pos] = s;
}

// ---------------- fast f32 GEMM (bf16 out): 128x128x16, 8x8/thread ----------------

template <int BM, int BN, int BK>
__global__ __launch_bounds__(256)
void gemm128_bf16(const float* __restrict__ A, const float* __restrict__ B,
                  __hip_bfloat16* __restrict__ C, int M, int N, int K) {
    __shared__ float As[BK][BM + 4];
    __shared__ float Bs[BK][BN + 4];
    const int bx = blockIdx.x * BN;
    const int by = blockIdx.y * BM;
    const int tid = threadIdx.x;
    const int tx = tid & 15;
    const int ty = tid >> 4;
    float acc[8][8] = {};
    for (int k0 = 0; k0 < K; k0 += BK) {
        for (int v = tid; v < BM * BK / 4; v += 256) {
            int row = v / (BK / 4);
            int k4 = (v % (BK / 4)) * 4;
            int gm = by + row;
            float4 val = {0.f, 0.f, 0.f, 0.f};
            if (gm < M) val = *(const float4*)&A[(size_t)gm * K + k0 + k4];
            As[k4 + 0][row] = val.x;
            As[k4 + 1][row] = val.y;
            As[k4 + 2][row] = val.z;
            As[k4 + 3][row] = val.w;
        }
        for (int v = tid; v < BK * BN / 4; v += 256) {
            int kk = v / (BN / 4);
            int c4 = (v % (BN / 4)) * 4;
            *(float4*)&Bs[kk][c4] = *(const float4*)&B[(size_t)(k0 + kk) * N + bx + c4];
        }
        __syncthreads();
#pragma unroll
        for (int kk = 0; kk < BK; kk++) {
            float4 a0 = *(float4*)&As[kk][ty * 4];
            float4 a1 = *(float4*)&As[kk][BM / 2 + ty * 4];
            float4 b0 = *(float4*)&Bs[kk][tx * 4];
            float4 b1 = *(float4*)&Bs[kk][BN / 2 + tx * 4];
            float a[8] = {a0.x, a0.y, a0.z, a0.w, a1.x, a1.y, a1.z, a1.w};
            float b[8] = {b0.x, b0.y, b0.z, b0.w, b1.x, b1.y, b1.z, b1.w};
#pragma unroll
            for (int i = 0; i < 8; i++)
#pragma unroll
                for (int j = 0; j < 8; j++) acc[i][j] += a[i] * b[j];
        }
        __syncthreads();
    }
#pragma unroll
    for (int i = 0; i < 8; i++) {
        int gm = by + (i < 4 ? ty * 4 + i : BM / 2 + ty * 4 + (i - 4));
        if (gm >= M) continue;
#pragma unroll
        for (int j = 0; j < 8; j++) {
            int gn = bx + (j < 4 ? tx * 4 + j : BN / 2 + tx * 4 + (j - 4));
            C[(size_t)gm * N + gn] = __float2bfloat16(acc[i][j]);
        }
    }
}

// ---------------- small GEMM (bf16 out) for layer 2 ----------------

template <int BM, int BN, int BK, int TM, int TN>
__global__ __launch_bounds__((BM / TM) * (BN / TN))
void gemm_small_bf16(const float* __restrict__ A, const float* __restrict__ B,
                     __hip_bfloat16* __restrict__ C, int M, int N, int K) {
    constexpr int TX = BN / TN;
    constexpr int NT = (BM / TM) * (BN / TN);
    __shared__ float As[BK][BM + 1];
    __shared__ float Bs[BK][BN];
    const int bx = blockIdx.x * BN;
    const int by = blockIdx.y * BM;
    const int tid = threadIdx.x;
    const int tx = tid % TX;
    const int ty = tid / TX;
    float acc[TM][TN] = {};
    for (int k0 = 0; k0 < K; k0 += BK) {
        for (int i = tid; i < BM * BK; i += NT) {
            int m = i / BK, kk = i % BK;
            int gm = by + m;
            As[kk][m] = (gm < M) ? A[(size_t)gm * K + (k0 + kk)] : 0.f;
        }
        for (int i = tid; i < BK * BN; i += NT) {
            int kk = i / BN, nn = i % BN;
            Bs[kk][nn] = B[(size_t)(k0 + kk) * N + (bx + nn)];
        }
        __syncthreads();
#pragma unroll
        for (int kk = 0; kk < BK; kk++) {
            float a[TM], b[TN];
#pragma unroll
            for (int i = 0; i < TM; i++) a[i] = As[kk][ty * TM + i];
#pragma unroll
            for (int j = 0; j < TN; j++) b[j] = Bs[kk][tx * TN + j];
#pragma unroll
            for (int i = 0; i < TM; i++)
#pragma unroll
                for (int j = 0; j < TN; j++) acc[i][j] += a[i] * b[j];
        }
        __syncthreads();
    }
    for (int i = 0; i < TM; i++) {
        int gm = by + ty * TM + i;
        if (gm < M) {
            for (int j = 0; j < TN; j++)
                C[(size_t)gm * N + bx + tx * TN + j] = __float2bfloat16(acc[i][j]);
        }
    }
}

// ---------------- per-node attention logits (bf16 h, 16B loads) ----------------

template <int H, int C>
__global__ void al_bf16(const __hip_bfloat16* __restrict__ hfeat, const float* __restrict__ a_src,
                        const float* __restrict__ a_dst, float* __restrict__ als,
                        float* __restrict__ ald, int N) {
    int i = blockIdx.x * blockDim.x + threadIdx.x;
    if (i >= N * H) return;
    int n = i / H, h = i % H;
    const __hip_bfloat16* hp = hfeat + (size_t)n * H * C + h * C;
    float s1 = 0.f, s2 = 0.f;
    for (int c0 = 0; c0 < C; c0 += 8) {
        ushort8 v = *(const ushort8*)(hp + c0);
#pragma unroll
        for (int k = 0; k < 8; k++) {
            float f = bf2f(v[k]);
            s1 += f * a_src[h * C + c0 + k];
            s2 += f * a_dst[h * C + c0 + k];
        }
    }
    als[i] = s1;
    ald[i] = s2;
}

// ---------------- per-node softmax + aggregate (vectorized gather) ----------------
// Layout: pass1 computes e per (edge,head), caches in LDS (CAP slots), tracks max.
// pass2 converts to exp in LDS + per-head sum. pass3: NG edge-groups, TPE=HC/8
// threads per edge, 16B ushort8 gathers, acc[8]/thread, one LDS reduce at end.

template <int H, int C, bool RELU>
__global__ __launch_bounds__((H * C < 64) ? 64 : H * C)
void gat_agg_v3(const __hip_bfloat16* __restrict__ hfeat, const float* __restrict__ als,
                const float* __restrict__ ald, const int* __restrict__ rowptr,
                const int* __restrict__ col, const float* __restrict__ bias,
                float* __restrict__ out, int N) {
    constexpr int HC = H * C;
    constexpr int BLOCK = (HC < 64) ? 64 : HC;
    constexpr int VEC = 8;
    constexpr int TPE = HC / VEC;      // threads per edge (H=8: 32, H=1: 4)
    constexpr int NG = BLOCK / TPE;    // parallel edge groups (8 / 16)
    constexpr int CAP = 128;           // LDS-cached edges per node
    constexpr int LOG2H = (H == 8) ? 3 : 0;

    const int n = blockIdx.x;
    const int tid = threadIdx.x;
    const int r0 = rowptr[n];
    const int deg = rowptr[n + 1] - r0;

    __shared__ float sald[H];
    __shared__ float smax[H];
    __shared__ float sinv[H];
    __shared__ float red[BLOCK];
    __shared__ float se[CAP * H];
    __shared__ float sacc[NG][HC];

    if (tid < H) sald[tid] = ald[(size_t)n * H + tid];
    __syncthreads();
    const int hw = tid & (H - 1);
    const float aldh = sald[hw];

    // ---- pass 1: e values (cached) + per-head max ----
    float lm = -INFINITY;
    for (int idx = tid; idx < deg * H; idx += BLOCK) {
        int j = idx >> LOG2H;
        int s = col[r0 + j];
        float e = als[(size_t)s * H + hw] + aldh;
        e = LRELU(e);
        if (idx < CAP * H) se[idx] = e;
        lm = fmaxf(lm, e);
    }
    red[tid] = lm;
    __syncthreads();
    for (int s = BLOCK / 2; s >= H; s >>= 1) {
        if (tid < s) red[tid] = fmaxf(red[tid], red[tid + s]);
        __syncthreads();
    }
    if (tid < H) smax[tid] = red[tid];
    __syncthreads();
    const float mh = smax[hw];

    // ---- pass 2: se := exp(e - max), per-head sum ----
    float lsum = 0.f;
    const int cap_elems = min(deg, CAP) * H;
    for (int idx = tid; idx < cap_elems; idx += BLOCK) {
        float ex = __expf(se[idx] - mh);
        se[idx] = ex;
        lsum += ex;
    }
    for (int idx = CAP * H + tid; idx < deg * H; idx += BLOCK) {  // rare tail
        int j = idx >> LOG2H;
        int s = col[r0 + j];
        float e = als[(size_t)s * H + hw] + aldh;
        e = LRELU(e);
        lsum += __expf(e - mh);
    }
    __syncthreads();
    red[tid] = lsum;
    __syncthreads();
    for (int s = BLOCK / 2; s >= H; s >>= 1) {
        if (tid < s) red[tid] += red[tid + s];
        __syncthreads();
    }
    if (tid < H) sinv[tid] = 1.0f / red[tid];
    __syncthreads();

    // ---- pass 3: vectorized weighted gather ----
    const int g = tid / TPE;           // edge group
    const int c = tid % TPE;           // vec-chunk within row
    const int head = (c * VEC) / C;
    const float mh3 = smax[head];
    float acc[VEC] = {};
    for (int j = g; j < deg; j += NG) {
        int s = col[r0 + j];
        float wv;
        if (j < CAP) {
            wv = se[j * H + head];
        } else {                        // rare fallback
            float e = als[(size_t)s * H + head] + sald[head];
            e = LRELU(e);
            wv = __expf(e - mh3);
        }
        ushort8 v = *(const ushort8*)(hfeat + (size_t)s * HC + c * VEC);
#pragma unroll
        for (int k = 0; k < VEC; k++) acc[k] += bf2f(v[k]) * wv;
    }
    float4 lo = {acc[0], acc[1], acc[2], acc[3]};
    float4 hi = {acc[4], acc[5], acc[6], acc[7]};
    *(float4*)&sacc[g][c * VEC] = lo;
    *(float4*)&sacc[g][c * VEC + 4] = hi;
    __syncthreads();

    if (tid < HC) {
        float v = 0.f;
#pragma unroll
        for (int gg = 0; gg < NG; gg++) v += sacc[gg][tid];
        v = v * sinv[tid / C] + bias[tid];
        if (RELU) v = fmaxf(v, 0.f);
        out[(size_t)n * HC + tid] = v;
    }
}

// ---------------- pooling + head ----------------

__global__ void pool_kernel(const float* __restrict__ h, const int* __restrict__ batch,
                            float* __restrict__ sums, int* __restrict__ cnt, int N) {
    int i = blockIdx.x * blockDim.x + threadIdx.x;
    if (i >= N * 32) return;
    int n = i >> 5, c = i & 31;
    int g = batch[n];
    atomicAdd(&sums[g * 32 + c], h[i]);
    if (c == 0) atomicAdd(&cnt[g], 1);
}

__global__ void final_kernel(const float* __restrict__ sums, const int* __restrict__ cnt,
                             const float* __restrict__ lin_w, const float* __restrict__ lin_b,
                             float* __restrict__ out) {
    int g = blockIdx.x;
    int o = threadIdx.x;  // 64
    __shared__ float p[32];
    if (o < 32) {
        float cn = fmaxf((float)cnt[g], 1.0f);
        p[o] = sums[g * 32 + o] / cn;
    }
    __syncthreads();
    float acc = lin_b[o];
    for (int c = 0; c < 32; c++) acc += p[c] * lin_w[c * 64 + o];
    out[g * 64 + o] = acc;
}

// ---------------- launch ----------------

extern "C" void kernel_launch(void* const* d_in, const int* in_sizes, int n_in,
                              void* d_out, int out_size, void* d_ws, size_t ws_size,
                              hipStream_t stream) {
    const float* x     = (const float*)d_in[0];
    const int*   ei    = (const int*)d_in[1];
    const int*   batch = (const int*)d_in[2];
    const float* W0    = (const float*)d_in[3];
    const float* a_s0  = (const float*)d_in[4];
    const float* a_d0  = (const float*)d_in[5];
    const float* b0    = (const float*)d_in[6];
    const float* W1    = (const float*)d_in[7];
    const float* a_s1  = (const float*)d_in[8];
    const float* a_d1  = (const float*)d_in[9];
    const float* b1    = (const float*)d_in[10];
    const float* W2    = (const float*)d_in[11];
    const float* a_s2  = (const float*)d_in[12];
    const float* a_d2  = (const float*)d_in[13];
    const float* b2    = (const float*)d_in[14];
    const float* lin_w = (const float*)d_in[15];
    const float* lin_b = (const float*)d_in[16];

    const int N = in_sizes[0] / 128;   // 50000
    const int E = in_sizes[1] / 2;     // 1600000
    const int Etot = E + N;
    const int* src = ei;
    const int* dst = ei + E;

    char* w = (char*)d_ws;
    size_t off = 0;
    auto alloc = [&](size_t bytes) -> void* {
        void* p = (void*)(w + off);
        off += (bytes + 255) & ~(size_t)255;
        return p;
    };
    int*   deg    = (int*)alloc((size_t)N * 4);
    int*   rowptr = (int*)alloc((size_t)(N + 1) * 4);
    int*   fill   = (int*)alloc((size_t)N * 4);
    int*   colA   = (int*)alloc((size_t)Etot * 4);
    float* als    = (float*)alloc((size_t)N * 8 * 4);
    float* ald    = (float*)alloc((size_t)N * 8 * 4);
    __hip_bfloat16* hb = (__hip_bfloat16*)alloc((size_t)N * 256 * 2);
    float* bufB   = (float*)alloc((size_t)N * 256 * 4);
    float* out2   = (float*)alloc((size_t)N * 32 * 4);
    float* sums   = (float*)alloc((size_t)256 * 32 * 4);
    int*   cnt    = (int*)alloc((size_t)256 * 4);

    hipMemsetAsync(deg, 0, (size_t)N * 4, stream);
    hipMemsetAsync(fill, 0, (size_t)N * 4, stream);
    hipMemsetAsync(sums, 0, (size_t)256 * 32 * 4, stream);
    hipMemsetAsync(cnt, 0, (size_t)256 * 4, stream);

    // CSR by dst (with self loops)
    deg_kernel<<<(Etot + 255) / 256, 256, 0, stream>>>(dst, deg, E, N);
    scan_kernel<<<1, 1024, 0, stream>>>(deg, rowptr, N);
    scatter_kernel<<<(Etot + 255) / 256, 256, 0, stream>>>(src, dst, rowptr, fill, colA, E, N);

    dim3 gemm_grid(256 / 128, (N + 127) / 128);

    // layer 0: K=128
    gemm128_bf16<128, 128, 16><<<gemm_grid, 256, 0, stream>>>(x, W0, hb, N, 256, 128);
    al_bf16<8, 32><<<(N * 8 + 255) / 256, 256, 0, stream>>>(hb, a_s0, a_d0, als, ald, N);
    gat_agg_v3<8, 32, true><<<N, 256, 0, stream>>>(hb, als, ald, rowptr, colA, b0, bufB, N);

    // layer 1: K=256
    gemm128_bf16<128, 128, 16><<<gemm_grid, 256, 0, stream>>>(bufB, W1, hb, N, 256, 256);
    al_bf16<8, 32><<<(N * 8 + 255) / 256, 256, 0, stream>>>(hb, a_s1, a_d1, als, ald, N);
    gat_agg_v3<8, 32, true><<<N, 256, 0, stream>>>(hb, als, ald, rowptr, colA, b1, bufB, N);

    // layer 2: heads=1, C=32
    gemm_small_bf16<128, 32, 16, 8, 2><<<dim3(1, (N + 127) / 128), 256, 0, stream>>>(bufB, W2, hb, N, 32, 256);
    al_bf16<1, 32><<<(N + 255) / 256, 256, 0, stream>>>(hb, a_s2, a_d2, als, ald, N);
    gat_agg_v3<1, 32, false><<<N, 64, 0, stream>>>(hb, als, ald, rowptr, colA, b2, out2, N);

    // pool + head
    pool_kernel<<<(N * 32 + 255) / 256, 256, 0, stream>>>(out2, batch, sums, cnt, N);
    final_kernel<<<256, 64, 0, stream>>>(sums, cnt, lin_w, lin_b, (float*)d_out);
}

// Round 4
// 883.889 us; speedup vs baseline: 1.3508x; 1.1113x over previous
//
#include <hip/hip_runtime.h>
#include <hip/hip_bf16.h>

// ---------------------------------------------------------------------------
// GAT (3 layers) + global mean pool + linear head.
// R4: per-edge softmax weights precomputed edge-parallel (coalesced, bf16,
// no max-shift needed: logits bounded), agg = contiguous w sweep + 2-deep
// pipelined gather, pool+head fused via sorted-batch binary search.
// ---------------------------------------------------------------------------

#define LRELU(x) ((x) >= 0.f ? (x) : 0.2f * (x))

typedef unsigned short ushort8 __attribute__((ext_vector_type(8)));

__device__ __forceinline__ float bf2f(unsigned short u) {
    return __uint_as_float(((unsigned)u) << 16);
}

// ---------------- CSR build ----------------

__global__ void deg_kernel(const int* __restrict__ dst, int* __restrict__ deg,
                           int E, int N) {
    int i = blockIdx.x * blockDim.x + threadIdx.x;
    if (i < E) atomicAdd(&deg[dst[i]], 1);
    else if (i < E + N) atomicAdd(&deg[i - E], 1);   // self loop
}

__global__ void scan_kernel(const int* __restrict__ deg, int* __restrict__ rowptr,
                            int n) {
    __shared__ int partial[1024];
    const int tid = threadIdx.x;
    const int chunk = (n + 1023) / 1024;
    const int start = min(tid * chunk, n);
    const int end = min(start + chunk, n);
    int s = 0;
    for (int i = start; i < end; i++) s += deg[i];
    partial[tid] = s;
    __syncthreads();
    for (int o = 1; o < 1024; o <<= 1) {
        int v = (tid >= o) ? partial[tid - o] : 0;
        __syncthreads();
        partial[tid] += v;
        __syncthreads();
    }
    int run = (tid == 0) ? 0 : partial[tid - 1];
    for (int i = start; i < end; i++) { rowptr[i] = run; run += deg[i]; }
    if (tid == 0) rowptr[n] = partial[1023];
}

__global__ void scatter2_kernel(const int* __restrict__ src, const int* __restrict__ dst,
                                const int* __restrict__ rowptr, int* __restrict__ fill,
                                int* __restrict__ col, int* __restrict__ dstA,
                                int E, int N) {
    int i = blockIdx.x * blockDim.x + threadIdx.x;
    int s, d;
    if (i < E) { s = src[i]; d = dst[i]; }
    else if (i < E + N) { s = i - E; d = s; }
    else return;
    int pos = rowptr[d] + atomicAdd(&fill[d], 1);
    col[pos] = s;
    dstA[pos] = d;
}

// graph start offsets from sorted batch (binary search)
__global__ void gstart_kernel(const int* __restrict__ batch, int* __restrict__ gstart,
                              int N, int G) {
    int g = blockIdx.x * blockDim.x + threadIdx.x;
    if (g > G) return;
    int lo = 0, hi = N;
    while (lo < hi) { int mid = (lo + hi) >> 1; if (batch[mid] < g) lo = mid + 1; else hi = mid; }
    gstart[g] = lo;
}

// ---------------- fast f32 GEMM (bf16 out): 128x128x16, 8x8/thread ----------------

template <int BM, int BN, int BK>
__global__ __launch_bounds__(256)
void gemm128_bf16(const float* __restrict__ A, const float* __restrict__ B,
                  __hip_bfloat16* __restrict__ C, int M, int N, int K) {
    __shared__ float As[BK][BM + 4];
    __shared__ float Bs[BK][BN + 4];
    const int bx = blockIdx.x * BN;
    const int by = blockIdx.y * BM;
    const int tid = threadIdx.x;
    const int tx = tid & 15;
    const int ty = tid >> 4;
    float acc[8][8] = {};
    for (int k0 = 0; k0 < K; k0 += BK) {
        for (int v = tid; v < BM * BK / 4; v += 256) {
            int row = v / (BK / 4);
            int k4 = (v % (BK / 4)) * 4;
            int gm = by + row;
            float4 val = {0.f, 0.f, 0.f, 0.f};
            if (gm < M) val = *(const float4*)&A[(size_t)gm * K + k0 + k4];
            As[k4 + 0][row] = val.x;
            As[k4 + 1][row] = val.y;
            As[k4 + 2][row] = val.z;
            As[k4 + 3][row] = val.w;
        }
        for (int v = tid; v < BK * BN / 4; v += 256) {
            int kk = v / (BN / 4);
            int c4 = (v % (BN / 4)) * 4;
            *(float4*)&Bs[kk][c4] = *(const float4*)&B[(size_t)(k0 + kk) * N + bx + c4];
        }
        __syncthreads();
#pragma unroll
        for (int kk = 0; kk < BK; kk++) {
            float4 a0 = *(float4*)&As[kk][ty * 4];
            float4 a1 = *(float4*)&As[kk][BM / 2 + ty * 4];
            float4 b0 = *(float4*)&Bs[kk][tx * 4];
            float4 b1 = *(float4*)&Bs[kk][BN / 2 + tx * 4];
            float a[8] = {a0.x, a0.y, a0.z, a0.w, a1.x, a1.y, a1.z, a1.w};
            float b[8] = {b0.x, b0.y, b0.z, b0.w, b1.x, b1.y, b1.z, b1.w};
#pragma unroll
            for (int i = 0; i < 8; i++)
#pragma unroll
                for (int j = 0; j < 8; j++) acc[i][j] += a[i] * b[j];
        }
        __syncthreads();
    }
#pragma unroll
    for (int i = 0; i < 8; i++) {
        int gm = by + (i < 4 ? ty * 4 + i : BM / 2 + ty * 4 + (i - 4));
        if (gm >= M) continue;
#pragma unroll
        for (int j = 0; j < 8; j++) {
            int gn = bx + (j < 4 ? tx * 4 + j : BN / 2 + tx * 4 + (j - 4));
            C[(size_t)gm * N + gn] = __float2bfloat16(acc[i][j]);
        }
    }
}

// ---------------- small GEMM (bf16 out) for layer 2 ----------------

template <int BM, int BN, int BK, int TM, int TN>
__global__ __launch_bounds__((BM / TM) * (BN / TN))
void gemm_small_bf16(const float* __restrict__ A, const float* __restrict__ B,
                     __hip_bfloat16* __restrict__ C, int M, int N, int K) {
    constexpr int TX = BN / TN;
    constexpr int NT = (BM / TM) * (BN / TN);
    __shared__ float As[BK][BM + 1];
    __shared__ float Bs[BK][BN];
    const int bx = blockIdx.x * BN;
    const int by = blockIdx.y * BM;
    const int tid = threadIdx.x;
    const int tx = tid % TX;
    const int ty = tid / TX;
    float acc[TM][TN] = {};
    for (int k0 = 0; k0 < K; k0 += BK) {
        for (int i = tid; i < BM * BK; i += NT) {
            int m = i / BK, kk = i % BK;
            int gm = by + m;
            As[kk][m] = (gm < M) ? A[(size_t)gm * K + (k0 + kk)] : 0.f;
        }
        for (int i = tid; i < BK * BN; i += NT) {
            int kk = i / BN, nn = i % BN;
            Bs[kk][nn] = B[(size_t)(k0 + kk) * N + (bx + nn)];
        }
        __syncthreads();
#pragma unroll
        for (int kk = 0; kk < BK; kk++) {
            float a[TM], b[TN];
#pragma unroll
            for (int i = 0; i < TM; i++) a[i] = As[kk][ty * TM + i];
#pragma unroll
            for (int j = 0; j < TN; j++) b[j] = Bs[kk][tx * TN + j];
#pragma unroll
            for (int i = 0; i < TM; i++)
#pragma unroll
                for (int j = 0; j < TN; j++) acc[i][j] += a[i] * b[j];
        }
        __syncthreads();
    }
    for (int i = 0; i < TM; i++) {
        int gm = by + ty * TM + i;
        if (gm < M) {
            for (int j = 0; j < TN; j++)
                C[(size_t)gm * N + bx + tx * TN + j] = __float2bfloat16(acc[i][j]);
        }
    }
}

// ---------------- per-node attention logits (bf16 h, 16B loads) ----------------

template <int H, int C>
__global__ void al_bf16(const __hip_bfloat16* __restrict__ hfeat, const float* __restrict__ a_src,
                        const float* __restrict__ a_dst, float* __restrict__ als,
                        float* __restrict__ ald, int N) {
    int i = blockIdx.x * blockDim.x + threadIdx.x;
    if (i >= N * H) return;
    int n = i / H, h = i % H;
    const __hip_bfloat16* hp = hfeat + (size_t)n * H * C + h * C;
    float s1 = 0.f, s2 = 0.f;
    for (int c0 = 0; c0 < C; c0 += 8) {
        ushort8 v = *(const ushort8*)(hp + c0);
#pragma unroll
        for (int k = 0; k < 8; k++) {
            float f = bf2f(v[k]);
            s1 += f * a_src[h * C + c0 + k];
            s2 += f * a_dst[h * C + c0 + k];
        }
    }
    als[i] = s1;
    ald[i] = s2;
}

// ---------------- per-edge softmax numerator (CSR order, coalesced) ----------------
// No max-shift: logits are bounded (|e| ~ O(1)); exp is exact-safe in f32,
// and softmax is shift-invariant so result matches the reference.

template <int H>
__global__ void edge_w_kernel(const float* __restrict__ als, const float* __restrict__ ald,
                              const int* __restrict__ col, const int* __restrict__ dstA,
                              __hip_bfloat16* __restrict__ wts, int Etot) {
    int i = blockIdx.x * blockDim.x + threadIdx.x;
    if (i >= Etot * H) return;
    int pos = i / H, h = i - pos * H;
    int s = col[pos], d = dstA[pos];
    float e = als[(size_t)s * H + h] + ald[(size_t)d * H + h];
    e = LRELU(e);
    wts[i] = __float2bfloat16(__expf(e));
}

// ---------------- per-node aggregate: contiguous w sweep + pipelined gather ----------------

template <int H, int C, bool RELU>
__global__ __launch_bounds__((H * C < 64) ? 64 : H * C)
void gat_agg_v4(const __hip_bfloat16* __restrict__ hfeat,
                const unsigned short* __restrict__ wts,   // bf16 bits, CSR-ordered [pos][H]
                const int* __restrict__ rowptr, const int* __restrict__ col,
                const float* __restrict__ bias, float* __restrict__ out, int N) {
    constexpr int HC = H * C;
    constexpr int BLOCK = (HC < 64) ? 64 : HC;
    constexpr int VEC = 8;
    constexpr int TPE = HC / VEC;      // threads per edge row
    constexpr int NG = BLOCK / TPE;    // parallel edge groups
    constexpr int NW = BLOCK / 64;     // waves
    constexpr int CAP = 128;           // LDS-cached edges (deg>CAP ~ never: Poisson(32))

    const int n = blockIdx.x;
    const int tid = threadIdx.x;
    const int r0 = rowptr[n];
    const int deg = rowptr[n + 1] - r0;

    __shared__ float se[CAP * H];
    __shared__ float swred[NW * H];
    __shared__ float ssum[H];
    __shared__ float sacc[NG][HC + 4];

    // ---- pass A: contiguous w load -> LDS cache + per-head sum ----
    const size_t wbase = (size_t)r0 * H;
    float lsum = 0.f;
    if (deg <= CAP) {
        for (int idx = tid; idx < deg * H; idx += BLOCK) {
            float v = bf2f(wts[wbase + idx]);
            se[idx] = v;
            lsum += v;
        }
    } else {
        for (int idx = tid; idx < deg * H; idx += BLOCK) {
            float v = bf2f(wts[wbase + idx]);
            if (idx < CAP * H) se[idx] = v;
            lsum += v;
        }
    }
#pragma unroll
    for (int off = H; off < 64; off <<= 1) lsum += __shfl_xor(lsum, off);
    if ((tid & 63) < H) swred[(tid >> 6) * H + (tid & (H - 1))] = lsum;
    __syncthreads();
    if (tid < H) {
        float s = 0.f;
#pragma unroll
        for (int ww = 0; ww < NW; ww++) s += swred[ww * H + tid];
        ssum[tid] = s;       // read only after the post-pass-B barrier
    }

    // ---- pass B: 2-deep pipelined vector gather ----
    const int g = tid / TPE;
    const int c = tid % TPE;
    const int head = (c * VEC) / C;
    float acc[VEC] = {};
    int j = g;
    if (deg <= CAP) {
        for (; j + NG < deg; j += 2 * NG) {
            int s0 = col[r0 + j];
            int s1 = col[r0 + j + NG];
            float w0 = se[j * H + head];
            float w1 = se[(j + NG) * H + head];
            ushort8 v0 = *(const ushort8*)(hfeat + (size_t)s0 * HC + c * VEC);
            ushort8 v1 = *(const ushort8*)(hfeat + (size_t)s1 * HC + c * VEC);
#pragma unroll
            for (int k = 0; k < VEC; k++) acc[k] += bf2f(v0[k]) * w0;
#pragma unroll
            for (int k = 0; k < VEC; k++) acc[k] += bf2f(v1[k]) * w1;
        }
        for (; j < deg; j += NG) {
            int s0 = col[r0 + j];
            float w0 = se[j * H + head];
            ushort8 v0 = *(const ushort8*)(hfeat + (size_t)s0 * HC + c * VEC);
#pragma unroll
            for (int k = 0; k < VEC; k++) acc[k] += bf2f(v0[k]) * w0;
        }
    } else {
        for (; j < deg; j += NG) {
            int s0 = col[r0 + j];
            float w0 = bf2f(wts[wbase + (size_t)j * H + head]);
            ushort8 v0 = *(const ushort8*)(hfeat + (size_t)s0 * HC + c * VEC);
#pragma unroll
            for (int k = 0; k < VEC; k++) acc[k] += bf2f(v0[k]) * w0;
        }
    }
    *(float4*)&sacc[g][c * VEC] = (float4){acc[0], acc[1], acc[2], acc[3]};
    *(float4*)&sacc[g][c * VEC + 4] = (float4){acc[4], acc[5], acc[6], acc[7]};
    __syncthreads();

    if (tid < HC) {
        float v = 0.f;
#pragma unroll
        for (int gg = 0; gg < NG; gg++) v += sacc[gg][tid];
        v = v / ssum[tid / C] + bias[tid];
        if (RELU) v = fmaxf(v, 0.f);
        out[(size_t)n * HC + tid] = v;
    }
}

// ---------------- fused pool + head (sorted batch, no atomics) ----------------

__global__ __launch_bounds__(256)
void pool_final_kernel(const float* __restrict__ h, const int* __restrict__ gstart,
                       const float* __restrict__ lin_w, const float* __restrict__ lin_b,
                       float* __restrict__ out) {
    const int g = blockIdx.x;
    const int tid = threadIdx.x;
    const int n0 = gstart[g], n1 = gstart[g + 1];
    const int r = tid >> 5, c = tid & 31;
    __shared__ float pp[4][32];
    __shared__ float pm[32];
    float acc = 0.f;
    for (int n = n0 + r; n < n1; n += 8) acc += h[(size_t)n * 32 + c];
    acc += __shfl_xor(acc, 32);              // combine row pairs within wave
    if ((tid & 63) < 32) pp[tid >> 6][c] = acc;
    __syncthreads();
    if (tid < 32) {
        float s = pp[0][tid] + pp[1][tid] + pp[2][tid] + pp[3][tid];
        pm[tid] = s / fmaxf((float)(n1 - n0), 1.f);
    }
    __syncthreads();
    if (tid < 64) {
        float a = lin_b[tid];
#pragma unroll 8
        for (int cc = 0; cc < 32; cc++) a += pm[cc] * lin_w[cc * 64 + tid];
        out[(size_t)g * 64 + tid] = a;
    }
}

// ---------------- launch ----------------

extern "C" void kernel_launch(void* const* d_in, const int* in_sizes, int n_in,
                              void* d_out, int out_size, void* d_ws, size_t ws_size,
                              hipStream_t stream) {
    const float* x     = (const float*)d_in[0];
    const int*   ei    = (const int*)d_in[1];
    const int*   batch = (const int*)d_in[2];
    const float* W0    = (const float*)d_in[3];
    const float* a_s0  = (const float*)d_in[4];
    const float* a_d0  = (const float*)d_in[5];
    const float* b0    = (const float*)d_in[6];
    const float* W1    = (const float*)d_in[7];
    const float* a_s1  = (const float*)d_in[8];
    const float* a_d1  = (const float*)d_in[9];
    const float* b1    = (const float*)d_in[10];
    const float* W2    = (const float*)d_in[11];
    const float* a_s2  = (const float*)d_in[12];
    const float* a_d2  = (const float*)d_in[13];
    const float* b2    = (const float*)d_in[14];
    const float* lin_w = (const float*)d_in[15];
    const float* lin_b = (const float*)d_in[16];

    const int N = in_sizes[0] / 128;   // 50000
    const int E = in_sizes[1] / 2;     // 1600000
    const int G = 256;
    const int Etot = E + N;
    const int* src = ei;
    const int* dst = ei + E;

    char* w = (char*)d_ws;
    size_t off = 0;
    auto alloc = [&](size_t bytes) -> void* {
        void* p = (void*)(w + off);
        off += (bytes + 255) & ~(size_t)255;
        return p;
    };
    int*   deg    = (int*)alloc((size_t)N * 4);
    int*   rowptr = (int*)alloc((size_t)(N + 1) * 4);
    int*   fill   = (int*)alloc((size_t)N * 4);
    int*   colA   = (int*)alloc((size_t)Etot * 4);
    int*   dstA   = (int*)alloc((size_t)Etot * 4);
    int*   gstart = (int*)alloc((size_t)(G + 1) * 4);
    float* als    = (float*)alloc((size_t)N * 8 * 4);
    float* ald    = (float*)alloc((size_t)N * 8 * 4);
    __hip_bfloat16* hb  = (__hip_bfloat16*)alloc((size_t)N * 256 * 2);
    __hip_bfloat16* wts = (__hip_bfloat16*)alloc((size_t)Etot * 8 * 2);
    float* bufB   = (float*)alloc((size_t)N * 256 * 4);
    float* out2   = (float*)alloc((size_t)N * 32 * 4);

    hipMemsetAsync(deg, 0, (size_t)N * 4, stream);
    hipMemsetAsync(fill, 0, (size_t)N * 4, stream);

    // CSR by dst (with self loops) + graph offsets
    deg_kernel<<<(Etot + 255) / 256, 256, 0, stream>>>(dst, deg, E, N);
    scan_kernel<<<1, 1024, 0, stream>>>(deg, rowptr, N);
    scatter2_kernel<<<(Etot + 255) / 256, 256, 0, stream>>>(src, dst, rowptr, fill, colA, dstA, E, N);
    gstart_kernel<<<2, 256, 0, stream>>>(batch, gstart, N, G);

    dim3 gemm_grid(256 / 128, (N + 127) / 128);

    // layer 0: K=128
    gemm128_bf16<128, 128, 16><<<gemm_grid, 256, 0, stream>>>(x, W0, hb, N, 256, 128);
    al_bf16<8, 32><<<(N * 8 + 255) / 256, 256, 0, stream>>>(hb, a_s0, a_d0, als, ald, N);
    edge_w_kernel<8><<<(Etot * 8 + 255) / 256, 256, 0, stream>>>(als, ald, colA, dstA, wts, Etot);
    gat_agg_v4<8, 32, true><<<N, 256, 0, stream>>>(hb, (const unsigned short*)wts, rowptr, colA, b0, bufB, N);

    // layer 1: K=256
    gemm128_bf16<128, 128, 16><<<gemm_grid, 256, 0, stream>>>(bufB, W1, hb, N, 256, 256);
    al_bf16<8, 32><<<(N * 8 + 255) / 256, 256, 0, stream>>>(hb, a_s1, a_d1, als, ald, N);
    edge_w_kernel<8><<<(Etot * 8 + 255) / 256, 256, 0, stream>>>(als, ald, colA, dstA, wts, Etot);
    gat_agg_v4<8, 32, true><<<N, 256, 0, stream>>>(hb, (const unsigned short*)wts, rowptr, colA, b1, bufB, N);

    // layer 2: heads=1, C=32
    gemm_small_bf16<128, 32, 16, 8, 2><<<dim3(1, (N + 127) / 128), 256, 0, stream>>>(bufB, W2, hb, N, 32, 256);
    al_bf16<1, 32><<<(N + 255) / 256, 256, 0, stream>>>(hb, a_s2, a_d2, als, ald, N);
    edge_w_kernel<1><<<(Etot + 255) / 256, 256, 0, stream>>>(als, ald, colA, dstA, wts, Etot);
    gat_agg_v4<1, 32, false><<<N, 64, 0, stream>>>(hb, (const unsigned short*)wts, rowptr, colA, b2, out2, N);

    // fused pool + head
    pool_final_kernel<<<G, 256, 0, stream>>>(out2, gstart, lin_w, lin_b, (float*)d_out);
}

// Round 5
// 757.540 us; speedup vs baseline: 1.5761x; 1.1668x over previous
//
#include <hip/hip_runtime.h>
#include <hip/hip_bf16.h>

// ---------------------------------------------------------------------------
// GAT (3 layers) + global mean pool + linear head.
// R5: (1) CSR build diet — scatter col-only with atomicAdd on rowptr itself
// (shifted convention), dstA via sequential expansion. (2) GEMMs moved to
// MFMA with error-free bf16 hi/lo splitting (3 MFMA terms ~= f32 GEMM).
// ---------------------------------------------------------------------------

#define LRELU(x) ((x) >= 0.f ? (x) : 0.2f * (x))

typedef unsigned short ushort8 __attribute__((ext_vector_type(8)));
typedef __attribute__((ext_vector_type(8))) short bf16x8;
typedef __attribute__((ext_vector_type(4))) float f32x4;

__device__ __forceinline__ float bf2f(unsigned short u) {
    return __uint_as_float(((unsigned)u) << 16);
}
__device__ __forceinline__ unsigned short f2bf(float f) {
    __hip_bfloat16 b = __float2bfloat16(f);
    return *reinterpret_cast<unsigned short*>(&b);
}

// ---------------- CSR build ----------------

__global__ void deg_kernel(const int* __restrict__ dst, int* __restrict__ deg,
                           int E, int N) {
    int i = blockIdx.x * blockDim.x + threadIdx.x;
    if (i < E) atomicAdd(&deg[dst[i]], 1);
    else if (i < E + N) atomicAdd(&deg[i - E], 1);   // self loop
}

__global__ void scan_kernel(const int* __restrict__ deg, int* __restrict__ rowptr,
                            int n) {
    __shared__ int partial[1024];
    const int tid = threadIdx.x;
    const int chunk = (n + 1023) / 1024;
    const int start = min(tid * chunk, n);
    const int end = min(start + chunk, n);
    int s = 0;
    for (int i = start; i < end; i++) s += deg[i];
    partial[tid] = s;
    __syncthreads();
    for (int o = 1; o < 1024; o <<= 1) {
        int v = (tid >= o) ? partial[tid - o] : 0;
        __syncthreads();
        partial[tid] += v;
        __syncthreads();
    }
    int run = (tid == 0) ? 0 : partial[tid - 1];
    for (int i = start; i < end; i++) { rowptr[i] = run; run += deg[i]; }
    if (tid == 0) rowptr[n] = partial[1023];
}

// position comes straight from atomicAdd on rowptr: afterwards rowptr[n] is the
// END of segment n (start = rowptr[n-1], or 0 for n=0) — "shifted convention".
__global__ void scatter_col_kernel(const int* __restrict__ src, const int* __restrict__ dst,
                                   int* __restrict__ rowptr, int* __restrict__ col,
                                   int E, int N) {
    int i = blockIdx.x * blockDim.x + threadIdx.x;
    int s, d;
    if (i < E) { s = src[i]; d = dst[i]; }
    else if (i < E + N) { s = i - E; d = s; }
    else return;
    int pos = atomicAdd(&rowptr[d], 1);
    col[pos] = s;
}

// dstA[pos] = n for pos in segment n — sequential (L2-friendly) writes.
__global__ void expand_dst_kernel(const int* __restrict__ rowptr, int* __restrict__ dstA,
                                  int N) {
    int n = blockIdx.x * blockDim.x + threadIdx.x;
    if (n >= N) return;
    int r0 = (n == 0) ? 0 : rowptr[n - 1];
    int r1 = rowptr[n];
    for (int p = r0; p < r1; p++) dstA[p] = n;
}

// graph start offsets from sorted batch (binary search)
__global__ void gstart_kernel(const int* __restrict__ batch, int* __restrict__ gstart,
                              int N, int G) {
    int g = blockIdx.x * blockDim.x + threadIdx.x;
    if (g > G) return;
    int lo = 0, hi = N;
    while (lo < hi) { int mid = (lo + hi) >> 1; if (batch[mid] < g) lo = mid + 1; else hi = mid; }
    gstart[g] = lo;
}

// ---------------- f32 -> bf16 hi/lo split kernels ----------------

__global__ void split_plain_kernel(const float* __restrict__ X, unsigned short* __restrict__ h,
                                   unsigned short* __restrict__ l, int n) {
    int i = blockIdx.x * blockDim.x + threadIdx.x;
    if (i >= n) return;
    float v = X[i];
    unsigned short hb = f2bf(v);
    h[i] = hb;
    l[i] = f2bf(v - bf2f(hb));
}

// W[K][N] -> Wt_hi/Wt_lo [N][K] (transposed so GEMM B-fragments are contiguous)
__global__ void splitT_kernel(const float* __restrict__ W, unsigned short* __restrict__ th,
                              unsigned short* __restrict__ tl, int K, int N) {
    int i = blockIdx.x * blockDim.x + threadIdx.x;
    if (i >= N * K) return;
    int n = i / K, k = i - n * K;
    float v = W[(size_t)k * N + n];
    unsigned short hb = f2bf(v);
    th[i] = hb;
    tl[i] = f2bf(v - bf2f(hb));
}

// ---------------- MFMA split-bf16 GEMM ----------------
// C[M,N](bf16) = (Ah+Al)[M,K] @ (Bh+Bl)[K,N], B given transposed [N][K].
// 3 MFMA terms (hh, hl, lh); f32 accumulate -> effectively f32 GEMM.

template <int BM, int BN, int WM, int WN>
__global__ __launch_bounds__(256)
void gemm_mfma_split(const unsigned short* __restrict__ Ah, const unsigned short* __restrict__ Al,
                     const unsigned short* __restrict__ Bth, const unsigned short* __restrict__ Btl,
                     unsigned short* __restrict__ Cc, int M, int N, int K) {
    constexpr int BK = 32;
    constexpr int LDK = BK + 8;              // pad to spread banks
    constexpr int MT = WM / 16, NT = WN / 16;
    constexpr int NWX = BN / WN;
    __shared__ __attribute__((aligned(16))) unsigned short Alds[2][BM][LDK];
    __shared__ __attribute__((aligned(16))) unsigned short Blds[2][BN][LDK];
    const int tid = threadIdx.x;
    const int lane = tid & 63;
    const int wave = tid >> 6;
    const int wx = wave % NWX, wy = wave / NWX;
    const int by = blockIdx.y * BM;
    const int bx = blockIdx.x * BN;
    const int r16 = lane & 15, kg = lane >> 4;

    f32x4 acc[MT][NT];
#pragma unroll
    for (int i = 0; i < MT; i++)
#pragma unroll
        for (int j = 0; j < NT; j++) acc[i][j] = (f32x4){0.f, 0.f, 0.f, 0.f};

    for (int k0 = 0; k0 < K; k0 += BK) {
        for (int v = tid; v < BM * BK / 8; v += 256) {
            int row = v >> 2;               // BK/8 == 4 chunks per row
            int kc = (v & 3) * 8;
            int gm = by + row;
            ushort8 hv = {0, 0, 0, 0, 0, 0, 0, 0};
            ushort8 lv = {0, 0, 0, 0, 0, 0, 0, 0};
            if (gm < M) {
                hv = *(const ushort8*)&Ah[(size_t)gm * K + k0 + kc];
                lv = *(const ushort8*)&Al[(size_t)gm * K + k0 + kc];
            }
            *(ushort8*)&Alds[0][row][kc] = hv;
            *(ushort8*)&Alds[1][row][kc] = lv;
        }
        for (int v = tid; v < BN * BK / 8; v += 256) {
            int row = v >> 2;
            int kc = (v & 3) * 8;
            int gn = bx + row;
            *(ushort8*)&Blds[0][row][kc] = *(const ushort8*)&Bth[(size_t)gn * K + k0 + kc];
            *(ushort8*)&Blds[1][row][kc] = *(const ushort8*)&Btl[(size_t)gn * K + k0 + kc];
        }
        __syncthreads();
        bf16x8 bh[NT], bl[NT];
#pragma unroll
        for (int j = 0; j < NT; j++) {
            bh[j] = *(const bf16x8*)&Blds[0][wx * WN + j * 16 + r16][kg * 8];
            bl[j] = *(const bf16x8*)&Blds[1][wx * WN + j * 16 + r16][kg * 8];
        }
#pragma unroll
        for (int i = 0; i < MT; i++) {
            bf16x8 ah = *(const bf16x8*)&Alds[0][wy * WM + i * 16 + r16][kg * 8];
            bf16x8 al2 = *(const bf16x8*)&Alds[1][wy * WM + i * 16 + r16][kg * 8];
#pragma unroll
            for (int j = 0; j < NT; j++) {
                acc[i][j] = __builtin_amdgcn_mfma_f32_16x16x32_bf16(ah, bh[j], acc[i][j], 0, 0, 0);
                acc[i][j] = __builtin_amdgcn_mfma_f32_16x16x32_bf16(ah, bl[j], acc[i][j], 0, 0, 0);
                acc[i][j] = __builtin_amdgcn_mfma_f32_16x16x32_bf16(al2, bh[j], acc[i][j], 0, 0, 0);
            }
        }
        __syncthreads();
    }
    // epilogue: D row = (lane>>4)*4 + reg, col = lane&15 (m89-verified mapping)
#pragma unroll
    for (int i = 0; i < MT; i++) {
#pragma unroll
        for (int r = 0; r < 4; r++) {
            int gm = by + wy * WM + i * 16 + kg * 4 + r;
            if (gm >= M) continue;
#pragma unroll
            for (int j = 0; j < NT; j++) {
                int gn = bx + wx * WN + j * 16 + r16;
                Cc[(size_t)gm * N + gn] = f2bf(acc[i][j][r]);
            }
        }
    }
}

// ---------------- per-node attention logits (bf16 h, 16B loads) ----------------

template <int H, int C>
__global__ void al_bf16(const unsigned short* __restrict__ hfeat, const float* __restrict__ a_src,
                        const float* __restrict__ a_dst, float* __restrict__ als,
                        float* __restrict__ ald, int N) {
    int i = blockIdx.x * blockDim.x + threadIdx.x;
    if (i >= N * H) return;
    int n = i / H, h = i % H;
    const unsigned short* hp = hfeat + (size_t)n * H * C + h * C;
    float s1 = 0.f, s2 = 0.f;
    for (int c0 = 0; c0 < C; c0 += 8) {
        ushort8 v = *(const ushort8*)(hp + c0);
#pragma unroll
        for (int k = 0; k < 8; k++) {
            float f = bf2f(v[k]);
            s1 += f * a_src[h * C + c0 + k];
            s2 += f * a_dst[h * C + c0 + k];
        }
    }
    als[i] = s1;
    ald[i] = s2;
}

// ---------------- per-edge softmax numerator (CSR order, coalesced) ----------------

template <int H>
__global__ void edge_w_kernel(const float* __restrict__ als, const float* __restrict__ ald,
                              const int* __restrict__ col, const int* __restrict__ dstA,
                              unsigned short* __restrict__ wts, int Etot) {
    int i = blockIdx.x * blockDim.x + threadIdx.x;
    if (i >= Etot * H) return;
    int pos = i / H, h = i - pos * H;
    int s = col[pos], d = dstA[pos];
    float e = als[(size_t)s * H + h] + ald[(size_t)d * H + h];
    e = LRELU(e);
    wts[i] = f2bf(__expf(e));
}

// ---------------- per-node aggregate (shifted rowptr; optional split output) ----------------

template <int H, int C, bool RELU, bool SPLIT>
__global__ __launch_bounds__((H * C < 64) ? 64 : H * C)
void gat_agg_v5(const unsigned short* __restrict__ hfeat,
                const unsigned short* __restrict__ wts,   // bf16 bits, CSR-ordered [pos][H]
                const int* __restrict__ rowptr,           // shifted: rowptr[n] = segment END
                const int* __restrict__ col,
                const float* __restrict__ bias, float* __restrict__ outF,
                unsigned short* __restrict__ outH, unsigned short* __restrict__ outL, int N) {
    constexpr int HC = H * C;
    constexpr int BLOCK = (HC < 64) ? 64 : HC;
    constexpr int VEC = 8;
    constexpr int TPE = HC / VEC;
    constexpr int NG = BLOCK / TPE;
    constexpr int NW = BLOCK / 64;
    constexpr int CAP = 128;

    const int n = blockIdx.x;
    const int tid = threadIdx.x;
    const int r0 = (n == 0) ? 0 : rowptr[n - 1];
    const int deg = rowptr[n] - r0;

    __shared__ float se[CAP * H];
    __shared__ float swred[NW * H];
    __shared__ float ssum[H];
    __shared__ float sacc[NG][HC + 4];

    // ---- pass A: contiguous w load -> LDS cache + per-head sum ----
    const size_t wbase = (size_t)r0 * H;
    float lsum = 0.f;
    if (deg <= CAP) {
        for (int idx = tid; idx < deg * H; idx += BLOCK) {
            float v = bf2f(wts[wbase + idx]);
            se[idx] = v;
            lsum += v;
        }
    } else {
        for (int idx = tid; idx < deg * H; idx += BLOCK) {
            float v = bf2f(wts[wbase + idx]);
            if (idx < CAP * H) se[idx] = v;
            lsum += v;
        }
    }
#pragma unroll
    for (int off = H; off < 64; off <<= 1) lsum += __shfl_xor(lsum, off);
    if ((tid & 63) < H) swred[(tid >> 6) * H + (tid & (H - 1))] = lsum;
    __syncthreads();
    if (tid < H) {
        float s = 0.f;
#pragma unroll
        for (int ww = 0; ww < NW; ww++) s += swred[ww * H + tid];
        ssum[tid] = s;       // read only after the post-pass-B barrier
    }

    // ---- pass B: 2-deep pipelined vector gather ----
    const int g = tid / TPE;
    const int c = tid % TPE;
    const int head = (c * VEC) / C;
    float acc[VEC] = {};
    int j = g;
    if (deg <= CAP) {
        for (; j + NG < deg; j += 2 * NG) {
            int s0 = col[r0 + j];
            int s1 = col[r0 + j + NG];
            float w0 = se[j * H + head];
            float w1 = se[(j + NG) * H + head];
            ushort8 v0 = *(const ushort8*)(hfeat + (size_t)s0 * HC + c * VEC);
            ushort8 v1 = *(const ushort8*)(hfeat + (size_t)s1 * HC + c * VEC);
#pragma unroll
            for (int k = 0; k < VEC; k++) acc[k] += bf2f(v0[k]) * w0;
#pragma unroll
            for (int k = 0; k < VEC; k++) acc[k] += bf2f(v1[k]) * w1;
        }
        for (; j < deg; j += NG) {
            int s0 = col[r0 + j];
            float w0 = se[j * H + head];
            ushort8 v0 = *(const ushort8*)(hfeat + (size_t)s0 * HC + c * VEC);
#pragma unroll
            for (int k = 0; k < VEC; k++) acc[k] += bf2f(v0[k]) * w0;
        }
    } else {
        for (; j < deg; j += NG) {
            int s0 = col[r0 + j];
            float w0 = bf2f(wts[wbase + (size_t)j * H + head]);
            ushort8 v0 = *(const ushort8*)(hfeat + (size_t)s0 * HC + c * VEC);
#pragma unroll
            for (int k = 0; k < VEC; k++) acc[k] += bf2f(v0[k]) * w0;
        }
    }
    *(float4*)&sacc[g][c * VEC] = (float4){acc[0], acc[1], acc[2], acc[3]};
    *(float4*)&sacc[g][c * VEC + 4] = (float4){acc[4], acc[5], acc[6], acc[7]};
    __syncthreads();

    if (tid < HC) {
        float v = 0.f;
#pragma unroll
        for (int gg = 0; gg < NG; gg++) v += sacc[gg][tid];
        v = v / ssum[tid / C] + bias[tid];
        if (RELU) v = fmaxf(v, 0.f);
        size_t idx = (size_t)n * HC + tid;
        if (SPLIT) {
            unsigned short hb = f2bf(v);
            outH[idx] = hb;
            outL[idx] = f2bf(v - bf2f(hb));
        } else {
            outF[idx] = v;
        }
    }
}

// ---------------- fused pool + head (sorted batch, no atomics) ----------------

__global__ __launch_bounds__(256)
void pool_final_kernel(const float* __restrict__ h, const int* __restrict__ gstart,
                       const float* __restrict__ lin_w, const float* __restrict__ lin_b,
                       float* __restrict__ out) {
    const int g = blockIdx.x;
    const int tid = threadIdx.x;
    const int n0 = gstart[g], n1 = gstart[g + 1];
    const int r = tid >> 5, c = tid & 31;
    __shared__ float pp[4][32];
    __shared__ float pm[32];
    float acc = 0.f;
    for (int n = n0 + r; n < n1; n += 8) acc += h[(size_t)n * 32 + c];
    acc += __shfl_xor(acc, 32);
    if ((tid & 63) < 32) pp[tid >> 6][c] = acc;
    __syncthreads();
    if (tid < 32) {
        float s = pp[0][tid] + pp[1][tid] + pp[2][tid] + pp[3][tid];
        pm[tid] = s / fmaxf((float)(n1 - n0), 1.f);
    }
    __syncthreads();
    if (tid < 64) {
        float a = lin_b[tid];
#pragma unroll 8
        for (int cc = 0; cc < 32; cc++) a += pm[cc] * lin_w[cc * 64 + tid];
        out[(size_t)g * 64 + tid] = a;
    }
}

// ---------------- launch ----------------

extern "C" void kernel_launch(void* const* d_in, const int* in_sizes, int n_in,
                              void* d_out, int out_size, void* d_ws, size_t ws_size,
                              hipStream_t stream) {
    const float* x     = (const float*)d_in[0];
    const int*   ei    = (const int*)d_in[1];
    const int*   batch = (const int*)d_in[2];
    const float* W0    = (const float*)d_in[3];
    const float* a_s0  = (const float*)d_in[4];
    const float* a_d0  = (const float*)d_in[5];
    const float* b0    = (const float*)d_in[6];
    const float* W1    = (const float*)d_in[7];
    const float* a_s1  = (const float*)d_in[8];
    const float* a_d1  = (const float*)d_in[9];
    const float* b1    = (const float*)d_in[10];
    const float* W2    = (const float*)d_in[11];
    const float* a_s2  = (const float*)d_in[12];
    const float* a_d2  = (const float*)d_in[13];
    const float* b2    = (const float*)d_in[14];
    const float* lin_w = (const float*)d_in[15];
    const float* lin_b = (const float*)d_in[16];

    const int N = in_sizes[0] / 128;   // 50000
    const int E = in_sizes[1] / 2;     // 1600000
    const int G = 256;
    const int Etot = E + N;
    const int* src = ei;
    const int* dst = ei + E;

    char* w = (char*)d_ws;
    size_t off = 0;
    auto alloc = [&](size_t bytes) -> void* {
        void* p = (void*)(w + off);
        off += (bytes + 255) & ~(size_t)255;
        return p;
    };
    int* deg    = (int*)alloc((size_t)N * 4);
    int* rowptr = (int*)alloc((size_t)(N + 1) * 4);
    int* colA   = (int*)alloc((size_t)Etot * 4);
    int* dstA   = (int*)alloc((size_t)Etot * 4);
    int* gstart = (int*)alloc((size_t)(G + 1) * 4);
    float* als  = (float*)alloc((size_t)N * 8 * 4);
    float* ald  = (float*)alloc((size_t)N * 8 * 4);
    unsigned short* hb  = (unsigned short*)alloc((size_t)N * 256 * 2);   // layer h (bf16)
    unsigned short* wts = (unsigned short*)alloc((size_t)Etot * 8 * 2);  // edge weights
    unsigned short* g0h = (unsigned short*)alloc((size_t)N * 256 * 2);   // agg out hi
    unsigned short* g0l = (unsigned short*)alloc((size_t)N * 256 * 2);   // agg out lo
    float* out2 = (float*)alloc((size_t)N * 32 * 4);
    unsigned short* w0h = (unsigned short*)alloc((size_t)128 * 256 * 2);
    unsigned short* w0l = (unsigned short*)alloc((size_t)128 * 256 * 2);
    unsigned short* w1h = (unsigned short*)alloc((size_t)256 * 256 * 2);
    unsigned short* w1l = (unsigned short*)alloc((size_t)256 * 256 * 2);
    unsigned short* w2h = (unsigned short*)alloc((size_t)256 * 32 * 2);
    unsigned short* w2l = (unsigned short*)alloc((size_t)256 * 32 * 2);
    // x hi/lo aliased into g0h (dead before agg0 writes g0h)
    unsigned short* xh = g0h;
    unsigned short* xl = g0h + (size_t)N * 128;

    hipMemsetAsync(deg, 0, (size_t)N * 4, stream);

    // CSR (shifted convention after scatter) + graph offsets
    deg_kernel<<<(Etot + 255) / 256, 256, 0, stream>>>(dst, deg, E, N);
    scan_kernel<<<1, 1024, 0, stream>>>(deg, rowptr, N);
    scatter_col_kernel<<<(Etot + 255) / 256, 256, 0, stream>>>(src, dst, rowptr, colA, E, N);
    expand_dst_kernel<<<(N + 255) / 256, 256, 0, stream>>>(rowptr, dstA, N);
    gstart_kernel<<<2, 256, 0, stream>>>(batch, gstart, N, G);

    // splits
    split_plain_kernel<<<(N * 128 + 255) / 256, 256, 0, stream>>>(x, xh, xl, N * 128);
    splitT_kernel<<<(128 * 256 + 255) / 256, 256, 0, stream>>>(W0, w0h, w0l, 128, 256);
    splitT_kernel<<<(256 * 256 + 255) / 256, 256, 0, stream>>>(W1, w1h, w1l, 256, 256);
    splitT_kernel<<<(256 * 32 + 255) / 256, 256, 0, stream>>>(W2, w2h, w2l, 256, 32);

    const int MB = (N + 127) / 128;

    // layer 0: K=128
    gemm_mfma_split<128, 128, 64, 64><<<dim3(2, MB), 256, 0, stream>>>(xh, xl, w0h, w0l, hb, N, 256, 128);
    al_bf16<8, 32><<<(N * 8 + 255) / 256, 256, 0, stream>>>(hb, a_s0, a_d0, als, ald, N);
    edge_w_kernel<8><<<((size_t)Etot * 8 + 255) / 256, 256, 0, stream>>>(als, ald, colA, dstA, wts, Etot);
    gat_agg_v5<8, 32, true, true><<<N, 256, 0, stream>>>(hb, wts, rowptr, colA, b0, nullptr, g0h, g0l, N);

    // layer 1: K=256
    gemm_mfma_split<128, 128, 64, 64><<<dim3(2, MB), 256, 0, stream>>>(g0h, g0l, w1h, w1l, hb, N, 256, 256);
    al_bf16<8, 32><<<(N * 8 + 255) / 256, 256, 0, stream>>>(hb, a_s1, a_d1, als, ald, N);
    edge_w_kernel<8><<<((size_t)Etot * 8 + 255) / 256, 256, 0, stream>>>(als, ald, colA, dstA, wts, Etot);
    gat_agg_v5<8, 32, true, true><<<N, 256, 0, stream>>>(hb, wts, rowptr, colA, b1, nullptr, g0h, g0l, N);

    // layer 2: heads=1, C=32, K=256 (hb reused as [N][32] bf16)
    gemm_mfma_split<128, 32, 32, 32><<<dim3(1, MB), 256, 0, stream>>>(g0h, g0l, w2h, w2l, hb, N, 32, 256);
    al_bf16<1, 32><<<(N + 255) / 256, 256, 0, stream>>>(hb, a_s2, a_d2, als, ald, N);
    edge_w_kernel<1><<<(Etot + 255) / 256, 256, 0, stream>>>(als, ald, colA, dstA, wts, Etot);
    gat_agg_v5<1, 32, false, false><<<N, 64, 0, stream>>>(hb, wts, rowptr, colA, b2, out2, nullptr, nullptr, N);

    // fused pool + head
    pool_final_kernel<<<G, 256, 0, stream>>>(out2, gstart, lin_w, lin_b, (float*)d_out);
}

// Round 6
// 708.676 us; speedup vs baseline: 1.6847x; 1.0690x over previous
//
#include <hip/hip_runtime.h>
#include <hip/hip_bf16.h>

// ---------------------------------------------------------------------------
// GAT (3 layers) + global mean pool + linear head.
// R6: binned CSR scatter (write locality), GEMM staging via global_load_lds
// (linear LDS, balanced banks), paired edge_w, 4-deep pipelined aggregation.
// ---------------------------------------------------------------------------

#define LRELU(x) ((x) >= 0.f ? (x) : 0.2f * (x))

typedef unsigned short ushort8 __attribute__((ext_vector_type(8)));
typedef __attribute__((ext_vector_type(8))) short bf16x8;
typedef __attribute__((ext_vector_type(4))) float f32x4;

__device__ __forceinline__ float bf2f(unsigned short u) {
    return __uint_as_float(((unsigned)u) << 16);
}
__device__ __forceinline__ unsigned short f2bf(float f) {
    __hip_bfloat16 b = __float2bfloat16(f);
    return *reinterpret_cast<unsigned short*>(&b);
}
__device__ __forceinline__ void gl_lds16(const unsigned short* g, unsigned short* l) {
    __builtin_amdgcn_global_load_lds((const __attribute__((address_space(1))) void*)g,
                                     (__attribute__((address_space(3))) void*)l, 16, 0, 0);
}

// ---------------- CSR build ----------------

__global__ void deg_kernel(const int* __restrict__ dst, int* __restrict__ deg,
                           int E, int N) {
    int i = blockIdx.x * blockDim.x + threadIdx.x;
    if (i < E) atomicAdd(&deg[dst[i]], 1);
    else if (i < E + N) atomicAdd(&deg[i - E], 1);   // self loop
}

__global__ void scan_kernel(const int* __restrict__ deg, int* __restrict__ rowptr,
                            int n) {
    __shared__ int partial[1024];
    const int tid = threadIdx.x;
    const int chunk = (n + 1023) / 1024;
    const int start = min(tid * chunk, n);
    const int end = min(start + chunk, n);
    int s = 0;
    for (int i = start; i < end; i++) s += deg[i];
    partial[tid] = s;
    __syncthreads();
    for (int o = 1; o < 1024; o <<= 1) {
        int v = (tid >= o) ? partial[tid - o] : 0;
        __syncthreads();
        partial[tid] += v;
        __syncthreads();
    }
    int run = (tid == 0) ? 0 : partial[tid - 1];
    for (int i = start; i < end; i++) { rowptr[i] = run; run += deg[i]; }
    if (tid == 0) rowptr[n] = partial[1023];
}

// Binned scatter: only dst in [lo,hi) handled per launch -> col write region
// ~1.6 MB stays L2-resident (kills the 64B-line write amplification).
// After all passes rowptr[n] = END of segment n (shifted convention).
__global__ void scatter_col_binned(const int* __restrict__ src, const int* __restrict__ dst,
                                   int* __restrict__ rowptr, int* __restrict__ col,
                                   int E, int N, int lo, int hi) {
    int i = blockIdx.x * blockDim.x + threadIdx.x;
    if (i < E) {
        int d = dst[i];
        if (d < lo || d >= hi) return;
        int pos = atomicAdd(&rowptr[d], 1);
        col[pos] = src[i];
    } else if (i < E + N) {
        int d = i - E;
        if (d < lo || d >= hi) return;
        int pos = atomicAdd(&rowptr[d], 1);
        col[pos] = d;
    }
}

// dstA[pos] = n for pos in segment n — sequential (L2-friendly) writes.
__global__ void expand_dst_kernel(const int* __restrict__ rowptr, int* __restrict__ dstA,
                                  int N) {
    int n = blockIdx.x * blockDim.x + threadIdx.x;
    if (n >= N) return;
    int r0 = (n == 0) ? 0 : rowptr[n - 1];
    int r1 = rowptr[n];
    for (int p = r0; p < r1; p++) dstA[p] = n;
}

__global__ void gstart_kernel(const int* __restrict__ batch, int* __restrict__ gstart,
                              int N, int G) {
    int g = blockIdx.x * blockDim.x + threadIdx.x;
    if (g > G) return;
    int lo = 0, hi = N;
    while (lo < hi) { int mid = (lo + hi) >> 1; if (batch[mid] < g) lo = mid + 1; else hi = mid; }
    gstart[g] = lo;
}

// ---------------- f32 -> bf16 hi/lo split kernels ----------------

__global__ void split_plain_kernel(const float* __restrict__ X, unsigned short* __restrict__ h,
                                   unsigned short* __restrict__ l, int n) {
    int i = blockIdx.x * blockDim.x + threadIdx.x;
    if (i >= n) return;
    float v = X[i];
    unsigned short hb = f2bf(v);
    h[i] = hb;
    l[i] = f2bf(v - bf2f(hb));
}

// W[K][N] -> Wt_hi/Wt_lo [N][K]
__global__ void splitT_kernel(const float* __restrict__ W, unsigned short* __restrict__ th,
                              unsigned short* __restrict__ tl, int K, int N) {
    int i = blockIdx.x * blockDim.x + threadIdx.x;
    if (i >= N * K) return;
    int n = i / K, k = i - n * K;
    float v = W[(size_t)k * N + n];
    unsigned short hb = f2bf(v);
    th[i] = hb;
    tl[i] = f2bf(v - bf2f(hb));
}

// ---------------- MFMA split-bf16 GEMM, global_load_lds staging ----------------
// C[M,N](bf16) = (Ah+Al)[M,K] @ (Bh+Bl)[K,N], B transposed [N][K].
// LDS linear [rows][BK=32] (64 B rows): fragment b128 reads tile the 32 banks
// in balance (canonical contiguous pattern) — no swizzle needed.

template <int BM, int BN, int WM, int WN>
__global__ __launch_bounds__(256)
void gemm_mfma_v2(const unsigned short* __restrict__ Ah, const unsigned short* __restrict__ Al,
                  const unsigned short* __restrict__ Bth, const unsigned short* __restrict__ Btl,
                  unsigned short* __restrict__ Cc, int M, int N, int K) {
    constexpr int BK = 32;
    constexpr int MT = WM / 16, NT = WN / 16;
    constexpr int NWX = BN / WN;
    __shared__ __attribute__((aligned(16))) unsigned short Ha[BM][BK];
    __shared__ __attribute__((aligned(16))) unsigned short La[BM][BK];
    __shared__ __attribute__((aligned(16))) unsigned short Hb[BN][BK];
    __shared__ __attribute__((aligned(16))) unsigned short Lb[BN][BK];
    const int tid = threadIdx.x;
    const int lane = tid & 63;
    const int wave = tid >> 6;
    const int wx = wave % NWX, wy = wave / NWX;
    const int by = blockIdx.y * BM;
    const int bx = blockIdx.x * BN;
    const int r16 = lane & 15, kg = lane >> 4;
    const int srow = lane >> 2, sslot = lane & 3;   // staging: 16 rows x 4 slots per wave-call

    f32x4 acc[MT][NT];
#pragma unroll
    for (int i = 0; i < MT; i++)
#pragma unroll
        for (int j = 0; j < NT; j++) acc[i][j] = (f32x4){0.f, 0.f, 0.f, 0.f};

    for (int k0 = 0; k0 < K; k0 += BK) {
        // A planes: each call DMA's 16 rows (64 lanes x 16B). Clamp OOB rows:
        // garbage only lands in C rows >= M, which are never stored.
        for (int t = wave; t < BM / 16; t += 4) {
            int gm = by + t * 16 + srow;
            if (gm >= M) gm = M - 1;
            const size_t goff = (size_t)gm * K + k0 + sslot * 8;
            gl_lds16(Ah + goff, &Ha[t * 16][0]);
            gl_lds16(Al + goff, &La[t * 16][0]);
        }
        for (int t = wave; t < BN / 16; t += 4) {
            int gn = bx + t * 16 + srow;
            const size_t goff = (size_t)gn * K + k0 + sslot * 8;
            gl_lds16(Bth + goff, &Hb[t * 16][0]);
            gl_lds16(Btl + goff, &Lb[t * 16][0]);
        }
        __syncthreads();
        bf16x8 bh[NT], bl[NT];
#pragma unroll
        for (int j = 0; j < NT; j++) {
            bh[j] = *(const bf16x8*)&Hb[wx * WN + j * 16 + r16][kg * 8];
            bl[j] = *(const bf16x8*)&Lb[wx * WN + j * 16 + r16][kg * 8];
        }
#pragma unroll
        for (int i = 0; i < MT; i++) {
            bf16x8 ah = *(const bf16x8*)&Ha[wy * WM + i * 16 + r16][kg * 8];
            bf16x8 al2 = *(const bf16x8*)&La[wy * WM + i * 16 + r16][kg * 8];
#pragma unroll
            for (int j = 0; j < NT; j++) {
                acc[i][j] = __builtin_amdgcn_mfma_f32_16x16x32_bf16(ah, bh[j], acc[i][j], 0, 0, 0);
                acc[i][j] = __builtin_amdgcn_mfma_f32_16x16x32_bf16(ah, bl[j], acc[i][j], 0, 0, 0);
                acc[i][j] = __builtin_amdgcn_mfma_f32_16x16x32_bf16(al2, bh[j], acc[i][j], 0, 0, 0);
            }
        }
        __syncthreads();
    }
    // epilogue: D row = (lane>>4)*4 + reg, col = lane&15 (m89-verified, R5-passed)
#pragma unroll
    for (int i = 0; i < MT; i++) {
#pragma unroll
        for (int r = 0; r < 4; r++) {
            int gm = by + wy * WM + i * 16 + kg * 4 + r;
            if (gm >= M) continue;
#pragma unroll
            for (int j = 0; j < NT; j++) {
                int gn = bx + wx * WN + j * 16 + r16;
                Cc[(size_t)gm * N + gn] = f2bf(acc[i][j][r]);
            }
        }
    }
}

// ---------------- per-node attention logits (bf16 h, 16B loads) ----------------

template <int H, int C>
__global__ void al_bf16(const unsigned short* __restrict__ hfeat, const float* __restrict__ a_src,
                        const float* __restrict__ a_dst, float* __restrict__ als,
                        float* __restrict__ ald, int N) {
    int i = blockIdx.x * blockDim.x + threadIdx.x;
    if (i >= N * H) return;
    int n = i / H, h = i % H;
    const unsigned short* hp = hfeat + (size_t)n * H * C + h * C;
    float s1 = 0.f, s2 = 0.f;
    for (int c0 = 0; c0 < C; c0 += 8) {
        ushort8 v = *(const ushort8*)(hp + c0);
#pragma unroll
        for (int k = 0; k < 8; k++) {
            float f = bf2f(v[k]);
            s1 += f * a_src[h * C + c0 + k];
            s2 += f * a_dst[h * C + c0 + k];
        }
    }
    als[i] = s1;
    ald[i] = s2;
}

// ---------------- per-edge softmax numerator ----------------
// H=8: one thread per (edge, head-pair) — float2 loads, packed bf16x2 store.

__global__ void edge_w_pair(const float* __restrict__ als, const float* __restrict__ ald,
                            const int* __restrict__ col, const int* __restrict__ dstA,
                            unsigned int* __restrict__ wts2, int Etot) {
    int i = blockIdx.x * blockDim.x + threadIdx.x;
    if (i >= Etot * 4) return;
    int pos = i >> 2, hp = i & 3;
    int s = col[pos], d = dstA[pos];
    float2 a = *(const float2*)&als[(size_t)s * 8 + hp * 2];
    float2 b = *(const float2*)&ald[(size_t)d * 8 + hp * 2];
    float e0 = a.x + b.x; e0 = LRELU(e0);
    float e1 = a.y + b.y; e1 = LRELU(e1);
    unsigned lo = f2bf(__expf(e0));
    unsigned hi = f2bf(__expf(e1));
    wts2[i] = lo | (hi << 16);
}

__global__ void edge_w_h1(const float* __restrict__ als, const float* __restrict__ ald,
                          const int* __restrict__ col, const int* __restrict__ dstA,
                          unsigned short* __restrict__ wts, int Etot) {
    int i = blockIdx.x * blockDim.x + threadIdx.x;
    if (i >= Etot) return;
    int s = col[i], d = dstA[i];
    float e = als[s] + ald[d];
    e = LRELU(e);
    wts[i] = f2bf(__expf(e));
}

// ---------------- per-node aggregate (4-deep pipelined gather) ----------------

template <int H, int C, bool RELU, bool SPLIT>
__global__ __launch_bounds__((H * C < 64) ? 64 : H * C)
void gat_agg_v6(const unsigned short* __restrict__ hfeat,
                const unsigned short* __restrict__ wts,   // bf16 bits, CSR-ordered [pos][H]
                const int* __restrict__ rowptr,           // shifted: rowptr[n] = segment END
                const int* __restrict__ col,
                const float* __restrict__ bias, float* __restrict__ outF,
                unsigned short* __restrict__ outH, unsigned short* __restrict__ outL, int N) {
    constexpr int HC = H * C;
    constexpr int BLOCK = (HC < 64) ? 64 : HC;
    constexpr int VEC = 8;
    constexpr int TPE = HC / VEC;
    constexpr int NG = BLOCK / TPE;
    constexpr int NW = BLOCK / 64;
    constexpr int CAP = 128;

    const int n = blockIdx.x;
    const int tid = threadIdx.x;
    const int r0 = (n == 0) ? 0 : rowptr[n - 1];
    const int deg = rowptr[n] - r0;

    __shared__ float se[CAP * H];
    __shared__ float swred[NW * H];
    __shared__ float ssum[H];
    __shared__ float sacc[NG][HC + 4];

    // ---- pass A: contiguous w load -> LDS cache + per-head sum ----
    const size_t wbase = (size_t)r0 * H;
    float lsum = 0.f;
    if (deg <= CAP) {
        for (int idx = tid; idx < deg * H; idx += BLOCK) {
            float v = bf2f(wts[wbase + idx]);
            se[idx] = v;
            lsum += v;
        }
    } else {
        for (int idx = tid; idx < deg * H; idx += BLOCK) {
            float v = bf2f(wts[wbase + idx]);
            if (idx < CAP * H) se[idx] = v;
            lsum += v;
        }
    }
#pragma unroll
    for (int off = H; off < 64; off <<= 1) lsum += __shfl_xor(lsum, off);
    if ((tid & 63) < H) swred[(tid >> 6) * H + (tid & (H - 1))] = lsum;
    __syncthreads();
    if (tid < H) {
        float s = 0.f;
#pragma unroll
        for (int ww = 0; ww < NW; ww++) s += swred[ww * H + tid];
        ssum[tid] = s;       // read only after the post-pass-B barrier
    }

    // ---- pass B: 4-deep pipelined vector gather ----
    const int g = tid / TPE;
    const int c = tid % TPE;
    const int head = (c * VEC) / C;
    float acc[VEC] = {};
    int j = g;
    if (deg <= CAP) {
        for (; j + 3 * NG < deg; j += 4 * NG) {
            int s0 = col[r0 + j];
            int s1 = col[r0 + j + NG];
            int s2 = col[r0 + j + 2 * NG];
            int s3 = col[r0 + j + 3 * NG];
            float w0 = se[j * H + head];
            float w1 = se[(j + NG) * H + head];
            float w2 = se[(j + 2 * NG) * H + head];
            float w3 = se[(j + 3 * NG) * H + head];
            ushort8 v0 = *(const ushort8*)(hfeat + (size_t)s0 * HC + c * VEC);
            ushort8 v1 = *(const ushort8*)(hfeat + (size_t)s1 * HC + c * VEC);
            ushort8 v2 = *(const ushort8*)(hfeat + (size_t)s2 * HC + c * VEC);
            ushort8 v3 = *(const ushort8*)(hfeat + (size_t)s3 * HC + c * VEC);
#pragma unroll
            for (int k = 0; k < VEC; k++) acc[k] += bf2f(v0[k]) * w0;
#pragma unroll
            for (int k = 0; k < VEC; k++) acc[k] += bf2f(v1[k]) * w1;
#pragma unroll
            for (int k = 0; k < VEC; k++) acc[k] += bf2f(v2[k]) * w2;
#pragma unroll
            for (int k = 0; k < VEC; k++) acc[k] += bf2f(v3[k]) * w3;
        }
        for (; j < deg; j += NG) {
            int s0 = col[r0 + j];
            float w0 = se[j * H + head];
            ushort8 v0 = *(const ushort8*)(hfeat + (size_t)s0 * HC + c * VEC);
#pragma unroll
            for (int k = 0; k < VEC; k++) acc[k] += bf2f(v0[k]) * w0;
        }
    } else {
        for (; j < deg; j += NG) {
            int s0 = col[r0 + j];
            float w0 = bf2f(wts[wbase + (size_t)j * H + head]);
            ushort8 v0 = *(const ushort8*)(hfeat + (size_t)s0 * HC + c * VEC);
#pragma unroll
            for (int k = 0; k < VEC; k++) acc[k] += bf2f(v0[k]) * w0;
        }
    }
    *(float4*)&sacc[g][c * VEC] = (float4){acc[0], acc[1], acc[2], acc[3]};
    *(float4*)&sacc[g][c * VEC + 4] = (float4){acc[4], acc[5], acc[6], acc[7]};
    __syncthreads();

    if (tid < HC) {
        float v = 0.f;
#pragma unroll
        for (int gg = 0; gg < NG; gg++) v += sacc[gg][tid];
        v = v / ssum[tid / C] + bias[tid];
        if (RELU) v = fmaxf(v, 0.f);
        size_t idx = (size_t)n * HC + tid;
        if (SPLIT) {
            unsigned short hb = f2bf(v);
            outH[idx] = hb;
            outL[idx] = f2bf(v - bf2f(hb));
        } else {
            outF[idx] = v;
        }
    }
}

// ---------------- fused pool + head (sorted batch, no atomics) ----------------

__global__ __launch_bounds__(256)
void pool_final_kernel(const float* __restrict__ h, const int* __restrict__ gstart,
                       const float* __restrict__ lin_w, const float* __restrict__ lin_b,
                       float* __restrict__ out) {
    const int g = blockIdx.x;
    const int tid = threadIdx.x;
    const int n0 = gstart[g], n1 = gstart[g + 1];
    const int r = tid >> 5, c = tid & 31;
    __shared__ float pp[4][32];
    __shared__ float pm[32];
    float acc = 0.f;
    for (int n = n0 + r; n < n1; n += 8) acc += h[(size_t)n * 32 + c];
    acc += __shfl_xor(acc, 32);
    if ((tid & 63) < 32) pp[tid >> 6][c] = acc;
    __syncthreads();
    if (tid < 32) {
        float s = pp[0][tid] + pp[1][tid] + pp[2][tid] + pp[3][tid];
        pm[tid] = s / fmaxf((float)(n1 - n0), 1.f);
    }
    __syncthreads();
    if (tid < 64) {
        float a = lin_b[tid];
#pragma unroll 8
        for (int cc = 0; cc < 32; cc++) a += pm[cc] * lin_w[cc * 64 + tid];
        out[(size_t)g * 64 + tid] = a;
    }
}

// ---------------- launch ----------------

extern "C" void kernel_launch(void* const* d_in, const int* in_sizes, int n_in,
                              void* d_out, int out_size, void* d_ws, size_t ws_size,
                              hipStream_t stream) {
    const float* x     = (const float*)d_in[0];
    const int*   ei    = (const int*)d_in[1];
    const int*   batch = (const int*)d_in[2];
    const float* W0    = (const float*)d_in[3];
    const float* a_s0  = (const float*)d_in[4];
    const float* a_d0  = (const float*)d_in[5];
    const float* b0    = (const float*)d_in[6];
    const float* W1    = (const float*)d_in[7];
    const float* a_s1  = (const float*)d_in[8];
    const float* a_d1  = (const float*)d_in[9];
    const float* b1    = (const float*)d_in[10];
    const float* W2    = (const float*)d_in[11];
    const float* a_s2  = (const float*)d_in[12];
    const float* a_d2  = (const float*)d_in[13];
    const float* b2    = (const float*)d_in[14];
    const float* lin_w = (const float*)d_in[15];
    const float* lin_b = (const float*)d_in[16];

    const int N = in_sizes[0] / 128;   // 50000
    const int E = in_sizes[1] / 2;     // 1600000
    const int G = 256;
    const int Etot = E + N;
    const int* src = ei;
    const int* dst = ei + E;

    char* w = (char*)d_ws;
    size_t off = 0;
    auto alloc = [&](size_t bytes) -> void* {
        void* p = (void*)(w + off);
        off += (bytes + 255) & ~(size_t)255;
        return p;
    };
    int* deg    = (int*)alloc((size_t)N * 4);
    int* rowptr = (int*)alloc((size_t)(N + 1) * 4);
    int* colA   = (int*)alloc((size_t)Etot * 4);
    int* dstA   = (int*)alloc((size_t)Etot * 4);
    int* gstart = (int*)alloc((size_t)(G + 1) * 4);
    float* als  = (float*)alloc((size_t)N * 8 * 4);
    float* ald  = (float*)alloc((size_t)N * 8 * 4);
    unsigned short* hb  = (unsigned short*)alloc((size_t)N * 256 * 2);   // layer h (bf16)
    unsigned short* wts = (unsigned short*)alloc((size_t)Etot * 8 * 2);  // edge weights
    unsigned short* g0h = (unsigned short*)alloc((size_t)N * 256 * 2);   // agg out hi
    unsigned short* g0l = (unsigned short*)alloc((size_t)N * 256 * 2);   // agg out lo
    float* out2 = (float*)alloc((size_t)N * 32 * 4);
    unsigned short* w0h = (unsigned short*)alloc((size_t)128 * 256 * 2);
    unsigned short* w0l = (unsigned short*)alloc((size_t)128 * 256 * 2);
    unsigned short* w1h = (unsigned short*)alloc((size_t)256 * 256 * 2);
    unsigned short* w1l = (unsigned short*)alloc((size_t)256 * 256 * 2);
    unsigned short* w2h = (unsigned short*)alloc((size_t)256 * 32 * 2);
    unsigned short* w2l = (unsigned short*)alloc((size_t)256 * 32 * 2);
    // x hi/lo aliased into g0h (dead before agg0 writes g0h)
    unsigned short* xh = g0h;
    unsigned short* xl = g0h + (size_t)N * 128;

    hipMemsetAsync(deg, 0, (size_t)N * 4, stream);

    // CSR (shifted convention) + graph offsets
    deg_kernel<<<(Etot + 255) / 256, 256, 0, stream>>>(dst, deg, E, N);
    scan_kernel<<<1, 1024, 0, stream>>>(deg, rowptr, N);
    for (int p = 0; p < 4; p++) {
        int lo = (int)((size_t)N * p / 4);
        int hi = (int)((size_t)N * (p + 1) / 4);
        scatter_col_binned<<<(Etot + 255) / 256, 256, 0, stream>>>(src, dst, rowptr, colA, E, N, lo, hi);
    }
    expand_dst_kernel<<<(N + 255) / 256, 256, 0, stream>>>(rowptr, dstA, N);
    gstart_kernel<<<2, 256, 0, stream>>>(batch, gstart, N, G);

    // splits
    split_plain_kernel<<<(N * 128 + 255) / 256, 256, 0, stream>>>(x, xh, xl, N * 128);
    splitT_kernel<<<(128 * 256 + 255) / 256, 256, 0, stream>>>(W0, w0h, w0l, 128, 256);
    splitT_kernel<<<(256 * 256 + 255) / 256, 256, 0, stream>>>(W1, w1h, w1l, 256, 256);
    splitT_kernel<<<(256 * 32 + 255) / 256, 256, 0, stream>>>(W2, w2h, w2l, 256, 32);

    const int MB = (N + 127) / 128;

    // layer 0: K=128
    gemm_mfma_v2<128, 128, 64, 64><<<dim3(2, MB), 256, 0, stream>>>(xh, xl, w0h, w0l, hb, N, 256, 128);
    al_bf16<8, 32><<<(N * 8 + 255) / 256, 256, 0, stream>>>(hb, a_s0, a_d0, als, ald, N);
    edge_w_pair<<<((size_t)Etot * 4 + 255) / 256, 256, 0, stream>>>(als, ald, colA, dstA, (unsigned int*)wts, Etot);
    gat_agg_v6<8, 32, true, true><<<N, 256, 0, stream>>>(hb, wts, rowptr, colA, b0, nullptr, g0h, g0l, N);

    // layer 1: K=256
    gemm_mfma_v2<128, 128, 64, 64><<<dim3(2, MB), 256, 0, stream>>>(g0h, g0l, w1h, w1l, hb, N, 256, 256);
    al_bf16<8, 32><<<(N * 8 + 255) / 256, 256, 0, stream>>>(hb, a_s1, a_d1, als, ald, N);
    edge_w_pair<<<((size_t)Etot * 4 + 255) / 256, 256, 0, stream>>>(als, ald, colA, dstA, (unsigned int*)wts, Etot);
    gat_agg_v6<8, 32, true, true><<<N, 256, 0, stream>>>(hb, wts, rowptr, colA, b1, nullptr, g0h, g0l, N);

    // layer 2: heads=1, C=32, K=256
    gemm_mfma_v2<128, 32, 32, 32><<<dim3(1, MB), 256, 0, stream>>>(g0h, g0l, w2h, w2l, hb, N, 32, 256);
    al_bf16<1, 32><<<(N + 255) / 256, 256, 0, stream>>>(hb, a_s2, a_d2, als, ald, N);
    edge_w_h1<<<(Etot + 255) / 256, 256, 0, stream>>>(als, ald, colA, dstA, wts, Etot);
    gat_agg_v6<1, 32, false, false><<<N, 64, 0, stream>>>(hb, wts, rowptr, colA, b2, out2, nullptr, nullptr, N);

    // fused pool + head
    pool_final_kernel<<<G, 256, 0, stream>>>(out2, gstart, lin_w, lin_b, (float*)d_out);
}

// Round 7
// 678.652 us; speedup vs baseline: 1.7593x; 1.0442x over previous
//
#include <hip/hip_runtime.h>
#include <hip/hip_bf16.h>

// ---------------------------------------------------------------------------
// GAT (3 layers) + global mean pool + linear head.
// R7: H=8 aggregation rebuilt as one-wave-per-node: zero barriers, zero
// cross-lane reduction in the gather, SGPR-based row addressing via
// readfirstlane (col is wave-uniform), ushort4 full-row-per-instruction loads.
// ---------------------------------------------------------------------------

#define LRELU(x) ((x) >= 0.f ? (x) : 0.2f * (x))

typedef unsigned short ushort8 __attribute__((ext_vector_type(8)));
typedef unsigned short ushort4v __attribute__((ext_vector_type(4)));
typedef __attribute__((ext_vector_type(8))) short bf16x8;
typedef __attribute__((ext_vector_type(4))) float f32x4;

__device__ __forceinline__ float bf2f(unsigned short u) {
    return __uint_as_float(((unsigned)u) << 16);
}
__device__ __forceinline__ unsigned short f2bf(float f) {
    __hip_bfloat16 b = __float2bfloat16(f);
    return *reinterpret_cast<unsigned short*>(&b);
}
__device__ __forceinline__ void gl_lds16(const unsigned short* g, unsigned short* l) {
    __builtin_amdgcn_global_load_lds((const __attribute__((address_space(1))) void*)g,
                                     (__attribute__((address_space(3))) void*)l, 16, 0, 0);
}

// ---------------- CSR build ----------------

__global__ void deg_kernel(const int* __restrict__ dst, int* __restrict__ deg,
                           int E, int N) {
    int i = blockIdx.x * blockDim.x + threadIdx.x;
    if (i < E) atomicAdd(&deg[dst[i]], 1);
    else if (i < E + N) atomicAdd(&deg[i - E], 1);   // self loop
}

__global__ void scan_kernel(const int* __restrict__ deg, int* __restrict__ rowptr,
                            int n) {
    __shared__ int partial[1024];
    const int tid = threadIdx.x;
    const int chunk = (n + 1023) / 1024;
    const int start = min(tid * chunk, n);
    const int end = min(start + chunk, n);
    int s = 0;
    for (int i = start; i < end; i++) s += deg[i];
    partial[tid] = s;
    __syncthreads();
    for (int o = 1; o < 1024; o <<= 1) {
        int v = (tid >= o) ? partial[tid - o] : 0;
        __syncthreads();
        partial[tid] += v;
        __syncthreads();
    }
    int run = (tid == 0) ? 0 : partial[tid - 1];
    for (int i = start; i < end; i++) { rowptr[i] = run; run += deg[i]; }
    if (tid == 0) rowptr[n] = partial[1023];
}

// Binned scatter (R6-proven): col write region stays L2-resident per pass.
// After all passes rowptr[n] = END of segment n (shifted convention).
__global__ void scatter_col_binned(const int* __restrict__ src, const int* __restrict__ dst,
                                   int* __restrict__ rowptr, int* __restrict__ col,
                                   int E, int N, int lo, int hi) {
    int i = blockIdx.x * blockDim.x + threadIdx.x;
    if (i < E) {
        int d = dst[i];
        if (d < lo || d >= hi) return;
        int pos = atomicAdd(&rowptr[d], 1);
        col[pos] = src[i];
    } else if (i < E + N) {
        int d = i - E;
        if (d < lo || d >= hi) return;
        int pos = atomicAdd(&rowptr[d], 1);
        col[pos] = d;
    }
}

__global__ void expand_dst_kernel(const int* __restrict__ rowptr, int* __restrict__ dstA,
                                  int N) {
    int n = blockIdx.x * blockDim.x + threadIdx.x;
    if (n >= N) return;
    int r0 = (n == 0) ? 0 : rowptr[n - 1];
    int r1 = rowptr[n];
    for (int p = r0; p < r1; p++) dstA[p] = n;
}

__global__ void gstart_kernel(const int* __restrict__ batch, int* __restrict__ gstart,
                              int N, int G) {
    int g = blockIdx.x * blockDim.x + threadIdx.x;
    if (g > G) return;
    int lo = 0, hi = N;
    while (lo < hi) { int mid = (lo + hi) >> 1; if (batch[mid] < g) lo = mid + 1; else hi = mid; }
    gstart[g] = lo;
}

// ---------------- f32 -> bf16 hi/lo split kernels ----------------

__global__ void split_plain_kernel(const float* __restrict__ X, unsigned short* __restrict__ h,
                                   unsigned short* __restrict__ l, int n) {
    int i = blockIdx.x * blockDim.x + threadIdx.x;
    if (i >= n) return;
    float v = X[i];
    unsigned short hb = f2bf(v);
    h[i] = hb;
    l[i] = f2bf(v - bf2f(hb));
}

__global__ void splitT_kernel(const float* __restrict__ W, unsigned short* __restrict__ th,
                              unsigned short* __restrict__ tl, int K, int N) {
    int i = blockIdx.x * blockDim.x + threadIdx.x;
    if (i >= N * K) return;
    int n = i / K, k = i - n * K;
    float v = W[(size_t)k * N + n];
    unsigned short hb = f2bf(v);
    th[i] = hb;
    tl[i] = f2bf(v - bf2f(hb));
}

// ---------------- MFMA split-bf16 GEMM, global_load_lds staging ----------------

template <int BM, int BN, int WM, int WN>
__global__ __launch_bounds__(256)
void gemm_mfma_v2(const unsigned short* __restrict__ Ah, const unsigned short* __restrict__ Al,
                  const unsigned short* __restrict__ Bth, const unsigned short* __restrict__ Btl,
                  unsigned short* __restrict__ Cc, int M, int N, int K) {
    constexpr int BK = 32;
    constexpr int MT = WM / 16, NT = WN / 16;
    constexpr int NWX = BN / WN;
    __shared__ __attribute__((aligned(16))) unsigned short Ha[BM][BK];
    __shared__ __attribute__((aligned(16))) unsigned short La[BM][BK];
    __shared__ __attribute__((aligned(16))) unsigned short Hb[BN][BK];
    __shared__ __attribute__((aligned(16))) unsigned short Lb[BN][BK];
    const int tid = threadIdx.x;
    const int lane = tid & 63;
    const int wave = tid >> 6;
    const int wx = wave % NWX, wy = wave / NWX;
    const int by = blockIdx.y * BM;
    const int bx = blockIdx.x * BN;
    const int r16 = lane & 15, kg = lane >> 4;
    const int srow = lane >> 2, sslot = lane & 3;

    f32x4 acc[MT][NT];
#pragma unroll
    for (int i = 0; i < MT; i++)
#pragma unroll
        for (int j = 0; j < NT; j++) acc[i][j] = (f32x4){0.f, 0.f, 0.f, 0.f};

    for (int k0 = 0; k0 < K; k0 += BK) {
        for (int t = wave; t < BM / 16; t += 4) {
            int gm = by + t * 16 + srow;
            if (gm >= M) gm = M - 1;
            const size_t goff = (size_t)gm * K + k0 + sslot * 8;
            gl_lds16(Ah + goff, &Ha[t * 16][0]);
            gl_lds16(Al + goff, &La[t * 16][0]);
        }
        for (int t = wave; t < BN / 16; t += 4) {
            int gn = bx + t * 16 + srow;
            const size_t goff = (size_t)gn * K + k0 + sslot * 8;
            gl_lds16(Bth + goff, &Hb[t * 16][0]);
            gl_lds16(Btl + goff, &Lb[t * 16][0]);
        }
        __syncthreads();
        bf16x8 bh[NT], bl[NT];
#pragma unroll
        for (int j = 0; j < NT; j++) {
            bh[j] = *(const bf16x8*)&Hb[wx * WN + j * 16 + r16][kg * 8];
            bl[j] = *(const bf16x8*)&Lb[wx * WN + j * 16 + r16][kg * 8];
        }
#pragma unroll
        for (int i = 0; i < MT; i++) {
            bf16x8 ah = *(const bf16x8*)&Ha[wy * WM + i * 16 + r16][kg * 8];
            bf16x8 al2 = *(const bf16x8*)&La[wy * WM + i * 16 + r16][kg * 8];
#pragma unroll
            for (int j = 0; j < NT; j++) {
                acc[i][j] = __builtin_amdgcn_mfma_f32_16x16x32_bf16(ah, bh[j], acc[i][j], 0, 0, 0);
                acc[i][j] = __builtin_amdgcn_mfma_f32_16x16x32_bf16(ah, bl[j], acc[i][j], 0, 0, 0);
                acc[i][j] = __builtin_amdgcn_mfma_f32_16x16x32_bf16(al2, bh[j], acc[i][j], 0, 0, 0);
            }
        }
        __syncthreads();
    }
#pragma unroll
    for (int i = 0; i < MT; i++) {
#pragma unroll
        for (int r = 0; r < 4; r++) {
            int gm = by + wy * WM + i * 16 + kg * 4 + r;
            if (gm >= M) continue;
#pragma unroll
            for (int j = 0; j < NT; j++) {
                int gn = bx + wx * WN + j * 16 + r16;
                Cc[(size_t)gm * N + gn] = f2bf(acc[i][j][r]);
            }
        }
    }
}

// ---------------- per-node attention logits (bf16 h, 16B loads) ----------------

template <int H, int C>
__global__ void al_bf16(const unsigned short* __restrict__ hfeat, const float* __restrict__ a_src,
                        const float* __restrict__ a_dst, float* __restrict__ als,
                        float* __restrict__ ald, int N) {
    int i = blockIdx.x * blockDim.x + threadIdx.x;
    if (i >= N * H) return;
    int n = i / H, h = i % H;
    const unsigned short* hp = hfeat + (size_t)n * H * C + h * C;
    float s1 = 0.f, s2 = 0.f;
    for (int c0 = 0; c0 < C; c0 += 8) {
        ushort8 v = *(const ushort8*)(hp + c0);
#pragma unroll
        for (int k = 0; k < 8; k++) {
            float f = bf2f(v[k]);
            s1 += f * a_src[h * C + c0 + k];
            s2 += f * a_dst[h * C + c0 + k];
        }
    }
    als[i] = s1;
    ald[i] = s2;
}

// ---------------- per-edge softmax numerator ----------------

__global__ void edge_w_pair(const float* __restrict__ als, const float* __restrict__ ald,
                            const int* __restrict__ col, const int* __restrict__ dstA,
                            unsigned int* __restrict__ wts2, int Etot) {
    int i = blockIdx.x * blockDim.x + threadIdx.x;
    if (i >= Etot * 4) return;
    int pos = i >> 2, hp = i & 3;
    int s = col[pos], d = dstA[pos];
    float2 a = *(const float2*)&als[(size_t)s * 8 + hp * 2];
    float2 b = *(const float2*)&ald[(size_t)d * 8 + hp * 2];
    float e0 = a.x + b.x; e0 = LRELU(e0);
    float e1 = a.y + b.y; e1 = LRELU(e1);
    unsigned lo = f2bf(__expf(e0));
    unsigned hi = f2bf(__expf(e1));
    wts2[i] = lo | (hi << 16);
}

__global__ void edge_w_h1(const float* __restrict__ als, const float* __restrict__ ald,
                          const int* __restrict__ col, const int* __restrict__ dstA,
                          unsigned short* __restrict__ wts, int Etot) {
    int i = blockIdx.x * blockDim.x + threadIdx.x;
    if (i >= Etot) return;
    int s = col[i], d = dstA[i];
    float e = als[s] + ald[d];
    e = LRELU(e);
    wts[i] = f2bf(__expf(e));
}

// ---------------- H=8 aggregate: one wave per node, barrier-free ----------------
// Lane owns output cols [lane*4, lane*4+4) (head q=lane>>3). Pass A: one
// ushort8 weight load/lane (elem e = head e), shfl-reduced head sums, se/scol
// staged to this wave's private LDS slice. Pass B: col is wave-uniform ->
// readfirstlane -> SGPR base; ushort4 loads (64 lanes x 8B = one 512B row per
// instruction); unroll-4 for MLP. No __syncthreads anywhere.

__global__ __launch_bounds__(256)
void gat_agg_w8(const unsigned short* __restrict__ hfeat,
                const unsigned short* __restrict__ wts,   // [pos][8] bf16 bits
                const int* __restrict__ rowptr,           // shifted: rowptr[n] = END
                const int* __restrict__ col,
                const float* __restrict__ bias,
                unsigned short* __restrict__ outH, unsigned short* __restrict__ outL,
                int N) {
    constexpr int CAP = 128;
    const int wid = threadIdx.x >> 6;
    const int lane = threadIdx.x & 63;
    const int n = blockIdx.x * 4 + wid;
    __shared__ float se_all[4][CAP * 8];
    __shared__ int scol_all[4][CAP];
    if (n >= N) return;
    float* se = se_all[wid];
    int* scol = scol_all[wid];

    const int r0 = (n == 0) ? 0 : rowptr[n - 1];
    const int deg = rowptr[n] - r0;
    const int dh8 = deg * 8;
    const size_t wbase = (size_t)r0 * 8;
    const int dcap = min(deg, CAP);

    // stage col -> LDS (coalesced)
    for (int j = lane; j < dcap; j += 64) scol[j] = col[r0 + j];

    // ---- pass A: weights -> se + per-head sums in registers ----
    float p0 = 0.f, p1 = 0.f, p2 = 0.f, p3 = 0.f, p4 = 0.f, p5 = 0.f, p6 = 0.f, p7 = 0.f;
    for (int base = 0; base < dh8; base += 512) {
        int idx = base + lane * 8;
        if (idx < dh8) {
            ushort8 v = *(const ushort8*)&wts[wbase + idx];
            float f0 = bf2f(v[0]), f1 = bf2f(v[1]), f2 = bf2f(v[2]), f3 = bf2f(v[3]);
            float f4 = bf2f(v[4]), f5 = bf2f(v[5]), f6 = bf2f(v[6]), f7 = bf2f(v[7]);
            p0 += f0; p1 += f1; p2 += f2; p3 += f3;
            p4 += f4; p5 += f5; p6 += f6; p7 += f7;
            if (idx < CAP * 8) {
                *(float4*)&se[idx] = (float4){f0, f1, f2, f3};
                *(float4*)&se[idx + 4] = (float4){f4, f5, f6, f7};
            }
        }
    }
#pragma unroll
    for (int m = 1; m < 64; m <<= 1) {
        p0 += __shfl_xor(p0, m); p1 += __shfl_xor(p1, m);
        p2 += __shfl_xor(p2, m); p3 += __shfl_xor(p3, m);
        p4 += __shfl_xor(p4, m); p5 += __shfl_xor(p5, m);
        p6 += __shfl_xor(p6, m); p7 += __shfl_xor(p7, m);
    }
    const int q = lane >> 3;                 // this lane's head in pass B
    float S = (q == 0) ? p0 : (q == 1) ? p1 : (q == 2) ? p2 : (q == 3) ? p3
            : (q == 4) ? p4 : (q == 5) ? p5 : (q == 6) ? p6 : p7;
    const float sinv = 1.0f / S;

    // ---- pass B: gather (full 512B row per wave instruction) ----
    const int cb = lane * 4;                 // this lane's 4 output cols
    float a0 = 0.f, a1 = 0.f, a2 = 0.f, a3 = 0.f;
    int j = 0;
    for (; j + 3 < dcap; j += 4) {
        int s0 = __builtin_amdgcn_readfirstlane(scol[j]);
        int s1 = __builtin_amdgcn_readfirstlane(scol[j + 1]);
        int s2 = __builtin_amdgcn_readfirstlane(scol[j + 2]);
        int s3 = __builtin_amdgcn_readfirstlane(scol[j + 3]);
        ushort4v v0 = *(const ushort4v*)(hfeat + (size_t)s0 * 256 + cb);
        ushort4v v1 = *(const ushort4v*)(hfeat + (size_t)s1 * 256 + cb);
        ushort4v v2 = *(const ushort4v*)(hfeat + (size_t)s2 * 256 + cb);
        ushort4v v3 = *(const ushort4v*)(hfeat + (size_t)s3 * 256 + cb);
        float w0 = se[j * 8 + q];
        float w1 = se[j * 8 + 8 + q];
        float w2 = se[j * 8 + 16 + q];
        float w3 = se[j * 8 + 24 + q];
        a0 += bf2f(v0[0]) * w0; a1 += bf2f(v0[1]) * w0; a2 += bf2f(v0[2]) * w0; a3 += bf2f(v0[3]) * w0;
        a0 += bf2f(v1[0]) * w1; a1 += bf2f(v1[1]) * w1; a2 += bf2f(v1[2]) * w1; a3 += bf2f(v1[3]) * w1;
        a0 += bf2f(v2[0]) * w2; a1 += bf2f(v2[1]) * w2; a2 += bf2f(v2[2]) * w2; a3 += bf2f(v2[3]) * w2;
        a0 += bf2f(v3[0]) * w3; a1 += bf2f(v3[1]) * w3; a2 += bf2f(v3[2]) * w3; a3 += bf2f(v3[3]) * w3;
    }
    for (; j < dcap; j++) {
        int s0 = __builtin_amdgcn_readfirstlane(scol[j]);
        ushort4v v0 = *(const ushort4v*)(hfeat + (size_t)s0 * 256 + cb);
        float w0 = se[j * 8 + q];
        a0 += bf2f(v0[0]) * w0; a1 += bf2f(v0[1]) * w0; a2 += bf2f(v0[2]) * w0; a3 += bf2f(v0[3]) * w0;
    }
    for (; j < deg; j++) {                   // deg > CAP fallback (essentially never)
        int s0 = col[r0 + j];
        float w0 = bf2f(wts[wbase + (size_t)j * 8 + q]);
        ushort4v v0 = *(const ushort4v*)(hfeat + (size_t)s0 * 256 + cb);
        a0 += bf2f(v0[0]) * w0; a1 += bf2f(v0[1]) * w0; a2 += bf2f(v0[2]) * w0; a3 += bf2f(v0[3]) * w0;
    }

    // ---- epilogue: normalize + bias + relu + hi/lo split store ----
    float4 b4 = *(const float4*)&bias[cb];
    float o0 = fmaxf(a0 * sinv + b4.x, 0.f);
    float o1 = fmaxf(a1 * sinv + b4.y, 0.f);
    float o2 = fmaxf(a2 * sinv + b4.z, 0.f);
    float o3 = fmaxf(a3 * sinv + b4.w, 0.f);
    unsigned short h0 = f2bf(o0), h1 = f2bf(o1), h2 = f2bf(o2), h3 = f2bf(o3);
    const size_t ob = (size_t)n * 256 + cb;
    *(ushort4v*)&outH[ob] = (ushort4v){h0, h1, h2, h3};
    *(ushort4v*)&outL[ob] = (ushort4v){f2bf(o0 - bf2f(h0)), f2bf(o1 - bf2f(h1)),
                                       f2bf(o2 - bf2f(h2)), f2bf(o3 - bf2f(h3))};
}

// ---------------- H=1 aggregate (layer 2) — R5 structure ----------------

__global__ __launch_bounds__(64)
void gat_agg_h1(const unsigned short* __restrict__ hfeat,
                const unsigned short* __restrict__ wts,
                const int* __restrict__ rowptr, const int* __restrict__ col,
                const float* __restrict__ bias, float* __restrict__ out, int N) {
    constexpr int HC = 32, VEC = 8, TPE = 4, NG = 16, CAP = 128;
    const int n = blockIdx.x;
    const int tid = threadIdx.x;
    const int r0 = (n == 0) ? 0 : rowptr[n - 1];
    const int deg = rowptr[n] - r0;

    __shared__ float se[CAP];
    __shared__ float sacc[NG][HC + 4];
    __shared__ float ssum_s;

    const size_t wbase = (size_t)r0;
    float lsum = 0.f;
    for (int idx = tid; idx < deg; idx += 64) {
        float v = bf2f(wts[wbase + idx]);
        if (idx < CAP) se[idx] = v;
        lsum += v;
    }
#pragma unroll
    for (int off = 1; off < 64; off <<= 1) lsum += __shfl_xor(lsum, off);
    if (tid == 0) ssum_s = lsum;

    const int g = tid / TPE;
    const int c = tid % TPE;
    float acc[VEC] = {};
    int j = g;
    for (; j + NG < deg && j + NG <= CAP; j += 2 * NG) {
        int s0 = col[r0 + j];
        int s1 = col[r0 + j + NG];
        float w0 = se[j];
        float w1 = se[j + NG];
        ushort8 v0 = *(const ushort8*)(hfeat + (size_t)s0 * HC + c * VEC);
        ushort8 v1 = *(const ushort8*)(hfeat + (size_t)s1 * HC + c * VEC);
#pragma unroll
        for (int k = 0; k < VEC; k++) acc[k] += bf2f(v0[k]) * w0;
#pragma unroll
        for (int k = 0; k < VEC; k++) acc[k] += bf2f(v1[k]) * w1;
    }
    for (; j < deg; j += NG) {
        int s0 = col[r0 + j];
        float w0 = (j < CAP) ? se[j] : bf2f(wts[wbase + j]);
        ushort8 v0 = *(const ushort8*)(hfeat + (size_t)s0 * HC + c * VEC);
#pragma unroll
        for (int k = 0; k < VEC; k++) acc[k] += bf2f(v0[k]) * w0;
    }
    *(float4*)&sacc[g][c * VEC] = (float4){acc[0], acc[1], acc[2], acc[3]};
    *(float4*)&sacc[g][c * VEC + 4] = (float4){acc[4], acc[5], acc[6], acc[7]};
    __syncthreads();

    if (tid < HC) {
        float v = 0.f;
#pragma unroll
        for (int gg = 0; gg < NG; gg++) v += sacc[gg][tid];
        v = v / ssum_s + bias[tid];
        out[(size_t)n * HC + tid] = v;
    }
}

// ---------------- fused pool + head (sorted batch, no atomics) ----------------

__global__ __launch_bounds__(256)
void pool_final_kernel(const float* __restrict__ h, const int* __restrict__ gstart,
                       const float* __restrict__ lin_w, const float* __restrict__ lin_b,
                       float* __restrict__ out) {
    const int g = blockIdx.x;
    const int tid = threadIdx.x;
    const int n0 = gstart[g], n1 = gstart[g + 1];
    const int r = tid >> 5, c = tid & 31;
    __shared__ float pp[4][32];
    __shared__ float pm[32];
    float acc = 0.f;
    for (int n = n0 + r; n < n1; n += 8) acc += h[(size_t)n * 32 + c];
    acc += __shfl_xor(acc, 32);
    if ((tid & 63) < 32) pp[tid >> 6][c] = acc;
    __syncthreads();
    if (tid < 32) {
        float s = pp[0][tid] + pp[1][tid] + pp[2][tid] + pp[3][tid];
        pm[tid] = s / fmaxf((float)(n1 - n0), 1.f);
    }
    __syncthreads();
    if (tid < 64) {
        float a = lin_b[tid];
#pragma unroll 8
        for (int cc = 0; cc < 32; cc++) a += pm[cc] * lin_w[cc * 64 + tid];
        out[(size_t)g * 64 + tid] = a;
    }
}

// ---------------- launch ----------------

extern "C" void kernel_launch(void* const* d_in, const int* in_sizes, int n_in,
                              void* d_out, int out_size, void* d_ws, size_t ws_size,
                              hipStream_t stream) {
    const float* x     = (const float*)d_in[0];
    const int*   ei    = (const int*)d_in[1];
    const int*   batch = (const int*)d_in[2];
    const float* W0    = (const float*)d_in[3];
    const float* a_s0  = (const float*)d_in[4];
    const float* a_d0  = (const float*)d_in[5];
    const float* b0    = (const float*)d_in[6];
    const float* W1    = (const float*)d_in[7];
    const float* a_s1  = (const float*)d_in[8];
    const float* a_d1  = (const float*)d_in[9];
    const float* b1    = (const float*)d_in[10];
    const float* W2    = (const float*)d_in[11];
    const float* a_s2  = (const float*)d_in[12];
    const float* a_d2  = (const float*)d_in[13];
    const float* b2    = (const float*)d_in[14];
    const float* lin_w = (const float*)d_in[15];
    const float* lin_b = (const float*)d_in[16];

    const int N = in_sizes[0] / 128;   // 50000
    const int E = in_sizes[1] / 2;     // 1600000
    const int G = 256;
    const int Etot = E + N;
    const int* src = ei;
    const int* dst = ei + E;

    char* w = (char*)d_ws;
    size_t off = 0;
    auto alloc = [&](size_t bytes) -> void* {
        void* p = (void*)(w + off);
        off += (bytes + 255) & ~(size_t)255;
        return p;
    };
    int* deg    = (int*)alloc((size_t)N * 4);
    int* rowptr = (int*)alloc((size_t)(N + 1) * 4);
    int* colA   = (int*)alloc((size_t)Etot * 4);
    int* dstA   = (int*)alloc((size_t)Etot * 4);
    int* gstart = (int*)alloc((size_t)(G + 1) * 4);
    float* als  = (float*)alloc((size_t)N * 8 * 4);
    float* ald  = (float*)alloc((size_t)N * 8 * 4);
    unsigned short* hb  = (unsigned short*)alloc((size_t)N * 256 * 2);
    unsigned short* wts = (unsigned short*)alloc((size_t)Etot * 8 * 2);
    unsigned short* g0h = (unsigned short*)alloc((size_t)N * 256 * 2);
    unsigned short* g0l = (unsigned short*)alloc((size_t)N * 256 * 2);
    float* out2 = (float*)alloc((size_t)N * 32 * 4);
    unsigned short* w0h = (unsigned short*)alloc((size_t)128 * 256 * 2);
    unsigned short* w0l = (unsigned short*)alloc((size_t)128 * 256 * 2);
    unsigned short* w1h = (unsigned short*)alloc((size_t)256 * 256 * 2);
    unsigned short* w1l = (unsigned short*)alloc((size_t)256 * 256 * 2);
    unsigned short* w2h = (unsigned short*)alloc((size_t)256 * 32 * 2);
    unsigned short* w2l = (unsigned short*)alloc((size_t)256 * 32 * 2);
    unsigned short* xh = g0h;
    unsigned short* xl = g0h + (size_t)N * 128;

    hipMemsetAsync(deg, 0, (size_t)N * 4, stream);

    deg_kernel<<<(Etot + 255) / 256, 256, 0, stream>>>(dst, deg, E, N);
    scan_kernel<<<1, 1024, 0, stream>>>(deg, rowptr, N);
    for (int p = 0; p < 4; p++) {
        int lo = (int)((size_t)N * p / 4);
        int hi = (int)((size_t)N * (p + 1) / 4);
        scatter_col_binned<<<(Etot + 255) / 256, 256, 0, stream>>>(src, dst, rowptr, colA, E, N, lo, hi);
    }
    expand_dst_kernel<<<(N + 255) / 256, 256, 0, stream>>>(rowptr, dstA, N);
    gstart_kernel<<<2, 256, 0, stream>>>(batch, gstart, N, G);

    split_plain_kernel<<<(N * 128 + 255) / 256, 256, 0, stream>>>(x, xh, xl, N * 128);
    splitT_kernel<<<(128 * 256 + 255) / 256, 256, 0, stream>>>(W0, w0h, w0l, 128, 256);
    splitT_kernel<<<(256 * 256 + 255) / 256, 256, 0, stream>>>(W1, w1h, w1l, 256, 256);
    splitT_kernel<<<(256 * 32 + 255) / 256, 256, 0, stream>>>(W2, w2h, w2l, 256, 32);

    const int MB = (N + 127) / 128;

    // layer 0: K=128
    gemm_mfma_v2<128, 128, 64, 64><<<dim3(2, MB), 256, 0, stream>>>(xh, xl, w0h, w0l, hb, N, 256, 128);
    al_bf16<8, 32><<<(N * 8 + 255) / 256, 256, 0, stream>>>(hb, a_s0, a_d0, als, ald, N);
    edge_w_pair<<<((size_t)Etot * 4 + 255) / 256, 256, 0, stream>>>(als, ald, colA, dstA, (unsigned int*)wts, Etot);
    gat_agg_w8<<<(N + 3) / 4, 256, 0, stream>>>(hb, wts, rowptr, colA, b0, g0h, g0l, N);

    // layer 1: K=256
    gemm_mfma_v2<128, 128, 64, 64><<<dim3(2, MB), 256, 0, stream>>>(g0h, g0l, w1h, w1l, hb, N, 256, 256);
    al_bf16<8, 32><<<(N * 8 + 255) / 256, 256, 0, stream>>>(hb, a_s1, a_d1, als, ald, N);
    edge_w_pair<<<((size_t)Etot * 4 + 255) / 256, 256, 0, stream>>>(als, ald, colA, dstA, (unsigned int*)wts, Etot);
    gat_agg_w8<<<(N + 3) / 4, 256, 0, stream>>>(hb, wts, rowptr, colA, b1, g0h, g0l, N);

    // layer 2: heads=1, C=32, K=256
    gemm_mfma_v2<128, 32, 32, 32><<<dim3(1, MB), 256, 0, stream>>>(g0h, g0l, w2h, w2l, hb, N, 32, 256);
    al_bf16<1, 32><<<(N + 255) / 256, 256, 0, stream>>>(hb, a_s2, a_d2, als, ald, N);
    edge_w_h1<<<(Etot + 255) / 256, 256, 0, stream>>>(als, ald, colA, dstA, wts, Etot);
    gat_agg_h1<<<N, 64, 0, stream>>>(hb, wts, rowptr, colA, b2, out2, N);

    // fused pool + head
    pool_final_kernel<<<G, 256, 0, stream>>>(out2, gstart, lin_w, lin_b, (float*)d_out);
}